// Round 4
// baseline (2174.984 us; speedup 1.0000x reference)
//
#include <hip/hip_runtime.h>
#include <hip/hip_bf16.h>

#define B_   2
#define S_   2048
#define T_   4096
#define DIM_ 1024
#define H_   16
#define KVH_ 4
#define HD_  64
#define I_   2048
#define N_   16
#define DTR_ 64
#define MB   ((size_t)1 << 20)

typedef __hip_bfloat16 bf16;
typedef __attribute__((ext_vector_type(8))) short short8;   // 8 bf16 (4 VGPRs)
typedef __attribute__((ext_vector_type(4))) short short4v;
typedef __attribute__((ext_vector_type(4))) float f32x4;

__device__ __forceinline__ float b2f(bf16 v){ return __bfloat162float(v); }
__device__ __forceinline__ bf16  f2b(float v){ return __float2bfloat16(v); }

__device__ __forceinline__ void async16(const void* g, void* l) {
  __builtin_amdgcn_global_load_lds((__attribute__((address_space(1))) void*)g,
                                   (__attribute__((address_space(3))) void*)l, 16, 0, 0);
}

// ---------------------------------------------------------------------------
// f32 -> bf16 cast, 4 elements/thread
// ---------------------------------------------------------------------------
__global__ __launch_bounds__(256)
void cast_f2b(const float* __restrict__ in, bf16* __restrict__ out, int n4)
{
  const int i = blockIdx.x * 256 + threadIdx.x;
  if (i >= n4) return;
  const float4 v = ((const float4*)in)[i];
  short4v o;
  o.x = (short)__builtin_bit_cast(unsigned short, f2b(v.x));
  o.y = (short)__builtin_bit_cast(unsigned short, f2b(v.y));
  o.z = (short)__builtin_bit_cast(unsigned short, f2b(v.z));
  o.w = (short)__builtin_bit_cast(unsigned short, f2b(v.w));
  *(short4v*)(out + (size_t)i * 4) = o;
}

// ---------------------------------------------------------------------------
// NT GEMM: C[M,N] = A[M,K] (row-major, lda) * W[N,K]^T (row-major, ldw)
// MODE 0: f32   MODE 1: bf16   MODE 2: f32 softplus(v+bias)  MODE 3: bf16 softplus(v+bias)
// 128x128 tile, BK=32, 4 waves, mfma_f32_16x16x32_bf16. N guarded so N=96 works.
// ---------------------------------------------------------------------------
template<int MODE>
__global__ __launch_bounds__(256)
void gemm_nt(const bf16* __restrict__ A, int lda,
             const bf16* __restrict__ W, int ldw,
             void* __restrict__ C, int ldc,
             const float* __restrict__ bias,
             int M, int N, int K)
{
  __shared__ __align__(16) bf16 As[128*32];
  __shared__ __align__(16) bf16 Bs[128*32];
  const int tid  = threadIdx.x;
  const int lane = tid & 63;
  const int wave = tid >> 6;
  const int l16  = lane & 15;
  const int quad = lane >> 4;
  const int wm   = (wave >> 1) << 6;
  const int wn   = (wave & 1) << 6;
  const int m0   = blockIdx.x << 7;
  const int n0   = blockIdx.y << 7;

  f32x4 acc[4][4];
  const f32x4 zero = {0.f, 0.f, 0.f, 0.f};
  #pragma unroll
  for (int i = 0; i < 4; i++)
    #pragma unroll
    for (int j = 0; j < 4; j++) acc[i][j] = zero;

  for (int k0 = 0; k0 < K; k0 += 32) {
    #pragma unroll
    for (int p = 0; p < 2; p++) {
      const int linear = ((p << 8) + tid) << 4;   // byte offset in 8KB tile
      const int row    = linear >> 6;             // 64 B per row (32 bf16)
      const int inrow  = linear & 63;
      async16(A + (size_t)(m0 + row) * lda + k0 + (inrow >> 1), (char*)As + linear);
      int wr = n0 + row; if (wr > N - 1) wr = N - 1;   // clamp for N=96
      async16(W + (size_t)wr * ldw + k0 + (inrow >> 1), (char*)Bs + linear);
    }
    __syncthreads();
    short8 af[4], bfr[4];
    #pragma unroll
    for (int mt = 0; mt < 4; mt++)
      af[mt] = *(const short8*)((const char*)As + ((wm + (mt << 4) + l16) << 6) + (quad << 4));
    #pragma unroll
    for (int nt = 0; nt < 4; nt++)
      bfr[nt] = *(const short8*)((const char*)Bs + ((wn + (nt << 4) + l16) << 6) + (quad << 4));
    #pragma unroll
    for (int mt = 0; mt < 4; mt++)
      #pragma unroll
      for (int nt = 0; nt < 4; nt++)
        acc[mt][nt] = __builtin_amdgcn_mfma_f32_16x16x32_bf16(af[mt], bfr[nt], acc[mt][nt], 0, 0, 0);
    __syncthreads();
  }

  #pragma unroll
  for (int mt = 0; mt < 4; mt++) {
    #pragma unroll
    for (int nt = 0; nt < 4; nt++) {
      const int col = n0 + wn + (nt << 4) + l16;
      if (col >= N) continue;
      #pragma unroll
      for (int r = 0; r < 4; r++) {
        const int row = m0 + wm + (mt << 4) + (quad << 2) + r;   // C/D: col=lane&15, row=quad*4+reg
        float v = acc[mt][nt][r];
        if (MODE >= 2) {
          v += bias[col];
          v = (v > 20.f) ? v : log1pf(__expf(v));
        }
        if (MODE == 0 || MODE == 2) ((float*)C)[(size_t)row * ldc + col] = v;
        else                        ((bf16*)C)[(size_t)row * ldc + col] = f2b(v);
      }
    }
  }
}

// ---------------------------------------------------------------------------
// QKV prep: RMSNorm(q,k) + RoPE(q,k) + q_gain, layout transforms.
// One wave per (token, head-slot). slots: 0-15 q heads, 16-19 k heads, 20-23 v.
// ---------------------------------------------------------------------------
__global__ __launch_bounds__(256)
void qkv_prep(const bf16* __restrict__ qraw, const bf16* __restrict__ kvraw,
              const float* __restrict__ q_gain,
              bf16* __restrict__ qn, bf16* __restrict__ kn, bf16* __restrict__ vt)
{
  const int wid  = blockIdx.x * 4 + (threadIdx.x >> 6);
  const int lane = threadIdx.x & 63;
  const int t    = wid / 24;
  const int slot = wid % 24;
  const int b = t >> 11, s = t & 2047;

  float val;
  if (slot < 16)       val = b2f(qraw [(size_t)t * 1024 + slot * 64 + lane]);
  else if (slot < 20)  val = b2f(kvraw[(size_t)t * 512  + (slot - 16) * 64 + lane]);
  else                 val = b2f(kvraw[(size_t)t * 512  + 256 + (slot - 20) * 64 + lane]);

  if (slot < 20) {
    float ss = val * val;
    #pragma unroll
    for (int off = 32; off; off >>= 1) ss += __shfl_xor(ss, off);
    val *= rsqrtf(ss * (1.0f / 64.0f) + 1.1920929e-07f);
    const int j = lane & 31;
    const float x1 = __shfl(val, j);
    const float x2 = __shfl(val, j + 32);
    const float inv = powf(10000.0f, -(float)j * (1.0f / 32.0f));
    const float ang = (float)s * inv;
    const float c = cosf(ang), sn = sinf(ang);
    val = (lane < 32) ? (x1 * c + x2 * sn) : (x2 * c - x1 * sn);
  }
  if (slot < 16) {
    val *= q_gain[slot];
    qn[((size_t)(b * 16 + slot) * 2048 + s) * 64 + lane] = f2b(val);
  } else if (slot < 20) {
    kn[((size_t)(b * 4 + (slot - 16)) * 2048 + s) * 64 + lane] = f2b(val);
  } else {
    vt[((size_t)(b * 4 + (slot - 20)) * 64 + lane) * 2048 + s] = f2b(val);
  }
}

// ---------------------------------------------------------------------------
// Flash attention (causal, GQA 16->4). Block = (b, h, 64 q-rows); 4 waves.
// ---------------------------------------------------------------------------
__global__ __launch_bounds__(256)
void attn_fwd(const bf16* __restrict__ qn, const bf16* __restrict__ kn,
              const bf16* __restrict__ vt, bf16* __restrict__ attn)
{
  __shared__ __align__(16) bf16 Plds[4][16][32];
  const int b = blockIdx.z, h = blockIdx.y, q0 = blockIdx.x * 64;
  const int wave = threadIdx.x >> 6, lane = threadIdx.x & 63;
  const int l16 = lane & 15, quad = lane >> 4;
  const int kvh = h >> 2;
  const bf16* Q  = qn + (size_t)(b * 16 + h)   * 2048 * 64;
  const bf16* Kp = kn + (size_t)(b * 4 + kvh)  * 2048 * 64;
  const bf16* Vt = vt + (size_t)(b * 4 + kvh)  * 64 * 2048;

  const int qrow_l = q0 + wave * 16 + l16;
  const short8 qf0 = *(const short8*)(Q + (size_t)qrow_l * 64 + quad * 8);
  const short8 qf1 = *(const short8*)(Q + (size_t)qrow_l * 64 + 32 + quad * 8);

  f32x4 acc[4];
  const f32x4 zero = {0.f, 0.f, 0.f, 0.f};
  #pragma unroll
  for (int i = 0; i < 4; i++) acc[i] = zero;
  float m_r[4], l_r[4];
  #pragma unroll
  for (int r = 0; r < 4; r++) { m_r[r] = -1e30f; l_r[r] = 0.f; }

  const int nkt = (q0 + 64) >> 5;
  for (int kt = 0; kt < nkt; kt++) {
    const int kb = kt << 5;
    const short8 kfA0 = *(const short8*)(Kp + (size_t)(kb + l16) * 64 + quad * 8);
    const short8 kfA1 = *(const short8*)(Kp + (size_t)(kb + l16) * 64 + 32 + quad * 8);
    const short8 kfB0 = *(const short8*)(Kp + (size_t)(kb + 16 + l16) * 64 + quad * 8);
    const short8 kfB1 = *(const short8*)(Kp + (size_t)(kb + 16 + l16) * 64 + 32 + quad * 8);
    f32x4 sA = zero, sB = zero;
    sA = __builtin_amdgcn_mfma_f32_16x16x32_bf16(qf0, kfA0, sA, 0, 0, 0);
    sA = __builtin_amdgcn_mfma_f32_16x16x32_bf16(qf1, kfA1, sA, 0, 0, 0);
    sB = __builtin_amdgcn_mfma_f32_16x16x32_bf16(qf0, kfB0, sB, 0, 0, 0);
    sB = __builtin_amdgcn_mfma_f32_16x16x32_bf16(qf1, kfB1, sB, 0, 0, 0);

    const int colA = kb + l16, colB = kb + 16 + l16;
    float pA[4], pB[4], alpha[4];
    #pragma unroll
    for (int r = 0; r < 4; r++) {
      const int row = q0 + wave * 16 + quad * 4 + r;
      float a  = sA[r] * 0.125f;
      float bb = sB[r] * 0.125f;
      if (colA > row) a  = -1e30f;
      if (colB > row) bb = -1e30f;
      float tm = fmaxf(a, bb);
      #pragma unroll
      for (int off = 8; off; off >>= 1) tm = fmaxf(tm, __shfl_xor(tm, off));
      const float nm = fmaxf(m_r[r], tm);
      alpha[r] = __expf(m_r[r] - nm);
      m_r[r] = nm;
      const float pa = __expf(a - nm), pb = __expf(bb - nm);
      pA[r] = pa; pB[r] = pb;
      float ps = pa + pb;
      #pragma unroll
      for (int off = 8; off; off >>= 1) ps += __shfl_xor(ps, off);
      l_r[r] = l_r[r] * alpha[r] + ps;
    }
    #pragma unroll
    for (int nt = 0; nt < 4; nt++)
      #pragma unroll
      for (int r = 0; r < 4; r++) acc[nt][r] *= alpha[r];

    __syncthreads();
    #pragma unroll
    for (int r = 0; r < 4; r++) {
      Plds[wave][quad * 4 + r][l16]      = f2b(pA[r]);
      Plds[wave][quad * 4 + r][16 + l16] = f2b(pB[r]);
    }
    __syncthreads();
    const short8 pf = *(const short8*)(&Plds[wave][l16][quad * 8]);
    #pragma unroll
    for (int nt = 0; nt < 4; nt++) {
      const short8 vf = *(const short8*)(Vt + (size_t)(nt * 16 + l16) * 2048 + kb + quad * 8);
      acc[nt] = __builtin_amdgcn_mfma_f32_16x16x32_bf16(pf, vf, acc[nt], 0, 0, 0);
    }
  }

  #pragma unroll
  for (int nt = 0; nt < 4; nt++)
    #pragma unroll
    for (int r = 0; r < 4; r++) {
      const int row = q0 + wave * 16 + quad * 4 + r;
      attn[((size_t)b * 2048 + row) * 1024 + h * 64 + nt * 16 + l16] = f2b(acc[nt][r] / l_r[r]);
    }
}

// ---------------------------------------------------------------------------
// Depthwise causal conv (K=4) + bias + SiLU on x_ssm [T,2048]
// ---------------------------------------------------------------------------
__global__ __launch_bounds__(256)
void conv_silu(const bf16* __restrict__ xssm, const float* __restrict__ cw,
               const float* __restrict__ cb, bf16* __restrict__ u)
{
  const int i = blockIdx.x * 256 + threadIdx.x;   // channel
  const int t = blockIdx.y;                        // token
  const int s = t & 2047;
  float acc = cb[i];
  #pragma unroll
  for (int kk = 0; kk < 4; kk++) {
    const int sp = s - 3 + kk;
    if (sp >= 0) acc += b2f(xssm[(size_t)(t - 3 + kk) * 2048 + i]) * cw[i * 4 + kk];
  }
  const float sig = 1.f / (1.f + __expf(-acc));
  u[(size_t)t * 2048 + i] = f2b(acc * sig);
}

// ---------------------------------------------------------------------------
// Selective-scan. Thread per (b, i, n): 65536 threads.
// ---------------------------------------------------------------------------
__global__ __launch_bounds__(256)
void ssm_scan(const bf16* __restrict__ delta, const bf16* __restrict__ u,
              const bf16* __restrict__ params, const float* __restrict__ A_log,
              const float* __restrict__ Dv, const bf16* __restrict__ gate,
              bf16* __restrict__ yout)
{
  const int gtid = blockIdx.x * 256 + threadIdx.x;
  const int n  = gtid & 15;
  const int ii = gtid >> 4;          // b*2048 + i
  const int b  = ii >> 11, i = ii & 2047;
  const float a  = -__expf(A_log[i * 16 + n]);
  const float Di = Dv[i];
  float state = 0.f;
  for (int t = 0; t < 2048; t++) {
    const size_t rb = (size_t)(b * 2048 + t);
    const float dt = b2f(delta[rb * 2048 + i]);
    const float ut = b2f(u[rb * 2048 + i]);
    const float Bn = b2f(params[rb * 96 + 64 + n]);
    const float Cn = b2f(params[rb * 96 + 80 + n]);
    const float dA = __expf(dt * a);
    state = state * dA + dt * ut * Bn;
    float y = state * Cn;
    #pragma unroll
    for (int off = 8; off; off >>= 1) y += __shfl_xor(y, off);
    if (n == 0) {
      const float g  = b2f(gate[rb * 2048 + i]);
      const float gs = g / (1.f + __expf(-g));
      yout[rb * 2048 + i] = f2b((y + ut * Di) * gs);
    }
  }
}

// ---------------------------------------------------------------------------
__global__ __launch_bounds__(256)
void merge_k(const bf16* __restrict__ attn, const bf16* __restrict__ mamba,
             const float* __restrict__ malpha, bf16* __restrict__ merged)
{
  const size_t idx = (size_t)blockIdx.x * 256 + threadIdx.x;
  const float al = 1.f / (1.f + __expf(-malpha[0]));
  merged[idx] = f2b(al * b2f(attn[idx]) + (1.f - al) * b2f(mamba[idx]));
}

// ---------------------------------------------------------------------------
extern "C" void kernel_launch(void* const* d_in, const int* in_sizes, int n_in,
                              void* d_out, int out_size, void* d_ws, size_t ws_size,
                              hipStream_t stream)
{
  const float* x_f     = (const float*)d_in[0];
  const float* Wm_f    = (const float*)d_in[1];
  const float* Wq_f    = (const float*)d_in[2];
  const float* Wkv_f   = (const float*)d_in[3];
  const float* q_gain  = (const float*)d_in[4];
  const float* conv_w  = (const float*)d_in[5];
  const float* conv_b  = (const float*)d_in[6];
  const float* Wxp_f   = (const float*)d_in[7];
  const float* Wdt_f   = (const float*)d_in[8];
  const float* b_dt    = (const float*)d_in[9];
  const float* A_log   = (const float*)d_in[10];
  const float* Dv      = (const float*)d_in[11];
  const float* Wmo_f   = (const float*)d_in[12];
  const float* Wp_f    = (const float*)d_in[13];
  const float* malpha  = (const float*)d_in[14];

  // Static arena with region reuse (peak 95 MB).
  char* wp = (char*)d_ws;
  bf16*  xb    = (bf16*)(wp + 0 * MB);
  bf16*  Wm_b  = (bf16*)(wp + 8 * MB);
  bf16*  Wq_b  = (bf16*)(wp + 16 * MB);
  bf16*  Wkv_b = (bf16*)(wp + 18 * MB);
  bf16*  xssm  = (bf16*)(wp + 19 * MB);
  bf16*  u     = (bf16*)(wp + 35 * MB);
  bf16*  gate  = (bf16*)(wp + 51 * MB);
  bf16*  qraw  = (bf16*)(wp + 67 * MB);
  bf16*  kvraw = (bf16*)(wp + 75 * MB);
  bf16*  dltb  = (bf16*)(wp + 79 * MB);
  // reused regions
  bf16*  qn    = (bf16*)(wp + 0 * MB);
  bf16*  kn    = (bf16*)(wp + 8 * MB);
  bf16*  vtb   = (bf16*)(wp + 10 * MB);
  bf16*  Wxp_b = (bf16*)(wp + 12 * MB);
  bf16*  Wdt_b = (bf16*)(wp + 12 * MB + 512 * 1024);
  bf16*  prm   = (bf16*)(wp + 13 * MB);
  bf16*  Wp_b  = (bf16*)(wp + 14 * MB);
  bf16*  attnb = (bf16*)(wp + 67 * MB);
  bf16*  Wmo_b = (bf16*)(wp + 75 * MB);
  bf16*  ybuf  = (bf16*)(wp + 19 * MB);
  bf16*  mam   = (bf16*)(wp + 51 * MB);
  bf16*  mrg   = (bf16*)(wp + 59 * MB);
  (void)ws_size; (void)in_sizes; (void)n_in; (void)out_size;

  auto cast = [&](const float* src, bf16* dst, int n) {
    const int n4 = n >> 2;
    cast_f2b<<<dim3((n4 + 255) / 256), 256, 0, stream>>>(src, dst, n4);
  };
  // stage 1: casts needed for input GEMMs
  cast(x_f,   xb,    T_ * 1024);
  cast(Wm_f,  Wm_b,  4096 * 1024);
  cast(Wq_f,  Wq_b,  1024 * 1024);
  cast(Wkv_f, Wkv_b, 512 * 1024);

  // stage 2: input projections
  gemm_nt<1><<<dim3(32, 16), 256, 0, stream>>>(xb, 1024, Wm_b,               1024, xssm, 2048, nullptr, T_, 2048, 1024);
  gemm_nt<1><<<dim3(32, 16), 256, 0, stream>>>(xb, 1024, Wm_b + 2048 * 1024, 1024, gate, 2048, nullptr, T_, 2048, 1024);
  gemm_nt<1><<<dim3(32, 8),  256, 0, stream>>>(xb, 1024, Wq_b,  1024, qraw,  1024, nullptr, T_, 1024, 1024);
  gemm_nt<1><<<dim3(32, 4),  256, 0, stream>>>(xb, 1024, Wkv_b, 1024, kvraw,  512, nullptr, T_,  512, 1024);

  // stage 3: qkv transform
  qkv_prep<<<dim3((T_ * 24) / 4), 256, 0, stream>>>(qraw, kvraw, q_gain, qn, kn, vtb);
  // stage 4: conv
  conv_silu<<<dim3(8, 4096), 256, 0, stream>>>(xssm, conv_w, conv_b, u);
  // stage 5: attention
  attn_fwd<<<dim3(32, 16, 2), 256, 0, stream>>>(qn, kn, vtb, attnb);

  // stage 6: remaining weight casts into freed regions
  cast(Wxp_f, Wxp_b, 96 * 2048);
  cast(Wdt_f, Wdt_b, 2048 * 64);
  cast(Wmo_f, Wmo_b, 1024 * 2048);
  cast(Wp_f,  Wp_b,  1024 * 1024);

  // stage 7: mamba tail
  gemm_nt<1><<<dim3(32, 1),  256, 0, stream>>>(u, 2048, Wxp_b, 2048, prm, 96, nullptr, T_, 96, 2048);
  gemm_nt<3><<<dim3(32, 16), 256, 0, stream>>>(prm, 96, Wdt_b, 64, dltb, 2048, b_dt, T_, 2048, 64);
  ssm_scan<<<dim3(256), 256, 0, stream>>>(dltb, u, prm, A_log, Dv, gate, ybuf);
  gemm_nt<1><<<dim3(32, 8),  256, 0, stream>>>(ybuf, 2048, Wmo_b, 2048, mam, 1024, nullptr, T_, 1024, 2048);

  // stage 8: merge + output projection — OUTPUT IS FLOAT32 (reference dtype)
  merge_k<<<dim3(16384), 256, 0, stream>>>(attnb, mam, malpha, mrg);
  gemm_nt<0><<<dim3(32, 8),  256, 0, stream>>>(mrg, 1024, Wp_b, 1024, (float*)d_out, 1024, nullptr, T_, 1024, 1024);
}

// Round 5
// 1045.721 us; speedup vs baseline: 2.0799x; 2.0799x over previous
//
#include <hip/hip_runtime.h>
#include <hip/hip_bf16.h>

#define B_   2
#define S_   2048
#define T_   4096
#define DIM_ 1024
#define H_   16
#define KVH_ 4
#define HD_  64
#define I_   2048
#define N_   16
#define DTR_ 64
#define MB   ((size_t)1 << 20)

typedef __hip_bfloat16 bf16;
typedef __attribute__((ext_vector_type(8))) short short8;   // 8 bf16 (4 VGPRs)
typedef __attribute__((ext_vector_type(4))) short short4v;
typedef __attribute__((ext_vector_type(4))) float f32x4;

__device__ __forceinline__ float b2f(bf16 v){ return __bfloat162float(v); }
__device__ __forceinline__ bf16  f2b(float v){ return __float2bfloat16(v); }

__device__ __forceinline__ void async16(const void* g, void* l) {
  __builtin_amdgcn_global_load_lds((__attribute__((address_space(1))) void*)g,
                                   (__attribute__((address_space(3))) void*)l, 16, 0, 0);
}

// ---------------------------------------------------------------------------
// f32 -> bf16 cast, 4 elements/thread
// ---------------------------------------------------------------------------
__global__ __launch_bounds__(256)
void cast_f2b(const float* __restrict__ in, bf16* __restrict__ out, int n4)
{
  const int i = blockIdx.x * 256 + threadIdx.x;
  if (i >= n4) return;
  const float4 v = ((const float4*)in)[i];
  short4v o;
  o.x = (short)__builtin_bit_cast(unsigned short, f2b(v.x));
  o.y = (short)__builtin_bit_cast(unsigned short, f2b(v.y));
  o.z = (short)__builtin_bit_cast(unsigned short, f2b(v.z));
  o.w = (short)__builtin_bit_cast(unsigned short, f2b(v.w));
  *(short4v*)(out + (size_t)i * 4) = o;
}

// ---------------------------------------------------------------------------
// NT GEMM: C[M,N] = A[M,K] (row-major, lda) * W[N,K]^T (row-major, ldw)
// MODE 0: f32   MODE 1: bf16   MODE 2: f32 softplus(v+bias)  MODE 3: bf16 softplus(v+bias)
// 128x128 tile, BK=32, 4 waves, mfma_f32_16x16x32_bf16. N guarded so N=96 works.
// ---------------------------------------------------------------------------
template<int MODE>
__global__ __launch_bounds__(256)
void gemm_nt(const bf16* __restrict__ A, int lda,
             const bf16* __restrict__ W, int ldw,
             void* __restrict__ C, int ldc,
             const float* __restrict__ bias,
             int M, int N, int K)
{
  __shared__ __align__(16) bf16 As[128*32];
  __shared__ __align__(16) bf16 Bs[128*32];
  const int tid  = threadIdx.x;
  const int lane = tid & 63;
  const int wave = tid >> 6;
  const int l16  = lane & 15;
  const int quad = lane >> 4;
  const int wm   = (wave >> 1) << 6;
  const int wn   = (wave & 1) << 6;
  const int m0   = blockIdx.x << 7;
  const int n0   = blockIdx.y << 7;

  f32x4 acc[4][4];
  const f32x4 zero = {0.f, 0.f, 0.f, 0.f};
  #pragma unroll
  for (int i = 0; i < 4; i++)
    #pragma unroll
    for (int j = 0; j < 4; j++) acc[i][j] = zero;

  for (int k0 = 0; k0 < K; k0 += 32) {
    #pragma unroll
    for (int p = 0; p < 2; p++) {
      const int linear = ((p << 8) + tid) << 4;   // byte offset in 8KB tile
      const int row    = linear >> 6;             // 64 B per row (32 bf16)
      const int inrow  = linear & 63;
      async16(A + (size_t)(m0 + row) * lda + k0 + (inrow >> 1), (char*)As + linear);
      int wr = n0 + row; if (wr > N - 1) wr = N - 1;   // clamp for N=96
      async16(W + (size_t)wr * ldw + k0 + (inrow >> 1), (char*)Bs + linear);
    }
    __syncthreads();
    short8 af[4], bfr[4];
    #pragma unroll
    for (int mt = 0; mt < 4; mt++)
      af[mt] = *(const short8*)((const char*)As + ((wm + (mt << 4) + l16) << 6) + (quad << 4));
    #pragma unroll
    for (int nt = 0; nt < 4; nt++)
      bfr[nt] = *(const short8*)((const char*)Bs + ((wn + (nt << 4) + l16) << 6) + (quad << 4));
    #pragma unroll
    for (int mt = 0; mt < 4; mt++)
      #pragma unroll
      for (int nt = 0; nt < 4; nt++)
        acc[mt][nt] = __builtin_amdgcn_mfma_f32_16x16x32_bf16(af[mt], bfr[nt], acc[mt][nt], 0, 0, 0);
    __syncthreads();
  }

  #pragma unroll
  for (int mt = 0; mt < 4; mt++) {
    #pragma unroll
    for (int nt = 0; nt < 4; nt++) {
      const int col = n0 + wn + (nt << 4) + l16;
      if (col >= N) continue;
      #pragma unroll
      for (int r = 0; r < 4; r++) {
        const int row = m0 + wm + (mt << 4) + (quad << 2) + r;   // C/D: col=lane&15, row=quad*4+reg
        float v = acc[mt][nt][r];
        if (MODE >= 2) {
          v += bias[col];
          v = (v > 20.f) ? v : log1pf(__expf(v));
        }
        if (MODE == 0 || MODE == 2) ((float*)C)[(size_t)row * ldc + col] = v;
        else                        ((bf16*)C)[(size_t)row * ldc + col] = f2b(v);
      }
    }
  }
}

// ---------------------------------------------------------------------------
// QKV prep: RMSNorm(q,k) + RoPE(q,k) + q_gain, layout transforms.
// ---------------------------------------------------------------------------
__global__ __launch_bounds__(256)
void qkv_prep(const bf16* __restrict__ qraw, const bf16* __restrict__ kvraw,
              const float* __restrict__ q_gain,
              bf16* __restrict__ qn, bf16* __restrict__ kn, bf16* __restrict__ vt)
{
  const int wid  = blockIdx.x * 4 + (threadIdx.x >> 6);
  const int lane = threadIdx.x & 63;
  const int t    = wid / 24;
  const int slot = wid % 24;
  const int b = t >> 11, s = t & 2047;

  float val;
  if (slot < 16)       val = b2f(qraw [(size_t)t * 1024 + slot * 64 + lane]);
  else if (slot < 20)  val = b2f(kvraw[(size_t)t * 512  + (slot - 16) * 64 + lane]);
  else                 val = b2f(kvraw[(size_t)t * 512  + 256 + (slot - 20) * 64 + lane]);

  if (slot < 20) {
    float ss = val * val;
    #pragma unroll
    for (int off = 32; off; off >>= 1) ss += __shfl_xor(ss, off);
    val *= rsqrtf(ss * (1.0f / 64.0f) + 1.1920929e-07f);
    const int j = lane & 31;
    const float x1 = __shfl(val, j);
    const float x2 = __shfl(val, j + 32);
    const float inv = powf(10000.0f, -(float)j * (1.0f / 32.0f));
    const float ang = (float)s * inv;
    const float c = cosf(ang), sn = sinf(ang);
    val = (lane < 32) ? (x1 * c + x2 * sn) : (x2 * c - x1 * sn);
  }
  if (slot < 16) {
    val *= q_gain[slot];
    qn[((size_t)(b * 16 + slot) * 2048 + s) * 64 + lane] = f2b(val);
  } else if (slot < 20) {
    kn[((size_t)(b * 4 + (slot - 16)) * 2048 + s) * 64 + lane] = f2b(val);
  } else {
    vt[((size_t)(b * 4 + (slot - 20)) * 64 + lane) * 2048 + s] = f2b(val);
  }
}

// ---------------------------------------------------------------------------
// Flash attention (causal, GQA 16->4). Block = (b, h, 64 q-rows); 4 waves.
// ---------------------------------------------------------------------------
__global__ __launch_bounds__(256)
void attn_fwd(const bf16* __restrict__ qn, const bf16* __restrict__ kn,
              const bf16* __restrict__ vt, bf16* __restrict__ attn)
{
  __shared__ __align__(16) bf16 Plds[4][16][32];
  const int b = blockIdx.z, h = blockIdx.y, q0 = blockIdx.x * 64;
  const int wave = threadIdx.x >> 6, lane = threadIdx.x & 63;
  const int l16 = lane & 15, quad = lane >> 4;
  const int kvh = h >> 2;
  const bf16* Q  = qn + (size_t)(b * 16 + h)   * 2048 * 64;
  const bf16* Kp = kn + (size_t)(b * 4 + kvh)  * 2048 * 64;
  const bf16* Vt = vt + (size_t)(b * 4 + kvh)  * 64 * 2048;

  const int qrow_l = q0 + wave * 16 + l16;
  const short8 qf0 = *(const short8*)(Q + (size_t)qrow_l * 64 + quad * 8);
  const short8 qf1 = *(const short8*)(Q + (size_t)qrow_l * 64 + 32 + quad * 8);

  f32x4 acc[4];
  const f32x4 zero = {0.f, 0.f, 0.f, 0.f};
  #pragma unroll
  for (int i = 0; i < 4; i++) acc[i] = zero;
  float m_r[4], l_r[4];
  #pragma unroll
  for (int r = 0; r < 4; r++) { m_r[r] = -1e30f; l_r[r] = 0.f; }

  const int nkt = (q0 + 64) >> 5;
  for (int kt = 0; kt < nkt; kt++) {
    const int kb = kt << 5;
    const short8 kfA0 = *(const short8*)(Kp + (size_t)(kb + l16) * 64 + quad * 8);
    const short8 kfA1 = *(const short8*)(Kp + (size_t)(kb + l16) * 64 + 32 + quad * 8);
    const short8 kfB0 = *(const short8*)(Kp + (size_t)(kb + 16 + l16) * 64 + quad * 8);
    const short8 kfB1 = *(const short8*)(Kp + (size_t)(kb + 16 + l16) * 64 + 32 + quad * 8);
    f32x4 sA = zero, sB = zero;
    sA = __builtin_amdgcn_mfma_f32_16x16x32_bf16(qf0, kfA0, sA, 0, 0, 0);
    sA = __builtin_amdgcn_mfma_f32_16x16x32_bf16(qf1, kfA1, sA, 0, 0, 0);
    sB = __builtin_amdgcn_mfma_f32_16x16x32_bf16(qf0, kfB0, sB, 0, 0, 0);
    sB = __builtin_amdgcn_mfma_f32_16x16x32_bf16(qf1, kfB1, sB, 0, 0, 0);

    const int colA = kb + l16, colB = kb + 16 + l16;
    float pA[4], pB[4], alpha[4];
    #pragma unroll
    for (int r = 0; r < 4; r++) {
      const int row = q0 + wave * 16 + quad * 4 + r;
      float a  = sA[r] * 0.125f;
      float bb = sB[r] * 0.125f;
      if (colA > row) a  = -1e30f;
      if (colB > row) bb = -1e30f;
      float tm = fmaxf(a, bb);
      #pragma unroll
      for (int off = 8; off; off >>= 1) tm = fmaxf(tm, __shfl_xor(tm, off));
      const float nm = fmaxf(m_r[r], tm);
      alpha[r] = __expf(m_r[r] - nm);
      m_r[r] = nm;
      const float pa = __expf(a - nm), pb = __expf(bb - nm);
      pA[r] = pa; pB[r] = pb;
      float ps = pa + pb;
      #pragma unroll
      for (int off = 8; off; off >>= 1) ps += __shfl_xor(ps, off);
      l_r[r] = l_r[r] * alpha[r] + ps;
    }
    #pragma unroll
    for (int nt = 0; nt < 4; nt++)
      #pragma unroll
      for (int r = 0; r < 4; r++) acc[nt][r] *= alpha[r];

    __syncthreads();
    #pragma unroll
    for (int r = 0; r < 4; r++) {
      Plds[wave][quad * 4 + r][l16]      = f2b(pA[r]);
      Plds[wave][quad * 4 + r][16 + l16] = f2b(pB[r]);
    }
    __syncthreads();
    const short8 pf = *(const short8*)(&Plds[wave][l16][quad * 8]);
    #pragma unroll
    for (int nt = 0; nt < 4; nt++) {
      const short8 vf = *(const short8*)(Vt + (size_t)(nt * 16 + l16) * 2048 + kb + quad * 8);
      acc[nt] = __builtin_amdgcn_mfma_f32_16x16x32_bf16(pf, vf, acc[nt], 0, 0, 0);
    }
  }

  #pragma unroll
  for (int nt = 0; nt < 4; nt++)
    #pragma unroll
    for (int r = 0; r < 4; r++) {
      const int row = q0 + wave * 16 + quad * 4 + r;
      attn[((size_t)b * 2048 + row) * 1024 + h * 64 + nt * 16 + l16] = f2b(acc[nt][r] / l_r[r]);
    }
}

// ---------------------------------------------------------------------------
// Depthwise causal conv (K=4) + bias + SiLU on x_ssm [T,2048]
// ---------------------------------------------------------------------------
__global__ __launch_bounds__(256)
void conv_silu(const bf16* __restrict__ xssm, const float* __restrict__ cw,
               const float* __restrict__ cb, bf16* __restrict__ u)
{
  const int i = blockIdx.x * 256 + threadIdx.x;   // channel
  const int t = blockIdx.y;                        // token
  const int s = t & 2047;
  float acc = cb[i];
  #pragma unroll
  for (int kk = 0; kk < 4; kk++) {
    const int sp = s - 3 + kk;
    if (sp >= 0) acc += b2f(xssm[(size_t)(t - 3 + kk) * 2048 + i]) * cw[i * 4 + kk];
  }
  const float sig = 1.f / (1.f + __expf(-acc));
  u[(size_t)t * 2048 + i] = f2b(acc * sig);
}

// ---------------------------------------------------------------------------
// Chunked two-pass selective scan. One block per (b,i); 256 threads =
// 16 n-states x 16 time-chunks of 128 steps. Linear recurrence decomposition:
// pass 1 computes per-chunk decay product P and zero-init final state F;
// LDS combine gives exact chunk init states; pass 2 replays and emits y.
// 4096 blocks -> 8 blocks/CU -> 32 waves/CU (vs 4 waves/CU monolithic).
// ---------------------------------------------------------------------------
__global__ __launch_bounds__(256)
void ssm_scan(const bf16* __restrict__ delta, const bf16* __restrict__ u,
              const bf16* __restrict__ params, const float* __restrict__ A_log,
              const float* __restrict__ Dv, const bf16* __restrict__ gate,
              bf16* __restrict__ yout)
{
  __shared__ float Pl[16][17], Fl[16][17], Il[16][17];
  const int blk = blockIdx.x;          // b*2048 + i
  const int b = blk >> 11, i = blk & 2047;
  const int n = threadIdx.x & 15, c = threadIdx.x >> 4;
  const float a  = -__expf(A_log[i * 16 + n]);
  const float Di = Dv[i];
  const size_t base = (size_t)b * 2048 + c * 128;

  // pass 1: local scan from zero
  float P = 1.f, F = 0.f;
  for (int j = 0; j < 128; j++) {
    const size_t rb = base + j;
    const float dt = b2f(delta[rb * 2048 + i]);
    const float ut = b2f(u[rb * 2048 + i]);
    const float Bn = b2f(params[rb * 96 + 64 + n]);
    const float dA = __expf(dt * a);
    P *= dA;
    F = F * dA + dt * ut * Bn;
  }
  Pl[n][c] = P; Fl[n][c] = F;
  __syncthreads();

  // combine: serial over 16 chunks, one thread per n
  if (threadIdx.x < 16) {
    const int nn = threadIdx.x;
    float s = 0.f;
    #pragma unroll
    for (int cc = 0; cc < 16; cc++) {
      Il[nn][cc] = s;
      s = Fl[nn][cc] + Pl[nn][cc] * s;
    }
  }
  __syncthreads();

  // pass 2: replay from exact init, emit y
  float state = Il[n][c];
  for (int j = 0; j < 128; j++) {
    const size_t rb = base + j;
    const float dt = b2f(delta[rb * 2048 + i]);
    const float ut = b2f(u[rb * 2048 + i]);
    const float Bn = b2f(params[rb * 96 + 64 + n]);
    const float Cn = b2f(params[rb * 96 + 80 + n]);
    const float dA = __expf(dt * a);
    state = state * dA + dt * ut * Bn;
    float y = state * Cn;
    y += __shfl_xor(y, 1); y += __shfl_xor(y, 2);
    y += __shfl_xor(y, 4); y += __shfl_xor(y, 8);
    if (n == 0) {
      const float g  = b2f(gate[rb * 2048 + i]);
      const float gs = g / (1.f + __expf(-g));
      yout[rb * 2048 + i] = f2b((y + ut * Di) * gs);
    }
  }
}

// ---------------------------------------------------------------------------
__global__ __launch_bounds__(256)
void merge_k(const bf16* __restrict__ attn, const bf16* __restrict__ mamba,
             const float* __restrict__ malpha, bf16* __restrict__ merged)
{
  const size_t idx = (size_t)blockIdx.x * 256 + threadIdx.x;
  const float al = 1.f / (1.f + __expf(-malpha[0]));
  merged[idx] = f2b(al * b2f(attn[idx]) + (1.f - al) * b2f(mamba[idx]));
}

// ---------------------------------------------------------------------------
extern "C" void kernel_launch(void* const* d_in, const int* in_sizes, int n_in,
                              void* d_out, int out_size, void* d_ws, size_t ws_size,
                              hipStream_t stream)
{
  const float* x_f     = (const float*)d_in[0];
  const float* Wm_f    = (const float*)d_in[1];
  const float* Wq_f    = (const float*)d_in[2];
  const float* Wkv_f   = (const float*)d_in[3];
  const float* q_gain  = (const float*)d_in[4];
  const float* conv_w  = (const float*)d_in[5];
  const float* conv_b  = (const float*)d_in[6];
  const float* Wxp_f   = (const float*)d_in[7];
  const float* Wdt_f   = (const float*)d_in[8];
  const float* b_dt    = (const float*)d_in[9];
  const float* A_log   = (const float*)d_in[10];
  const float* Dv      = (const float*)d_in[11];
  const float* Wmo_f   = (const float*)d_in[12];
  const float* Wp_f    = (const float*)d_in[13];
  const float* malpha  = (const float*)d_in[14];

  // Static arena with region reuse (peak 95 MB).
  char* wp = (char*)d_ws;
  bf16*  xb    = (bf16*)(wp + 0 * MB);
  bf16*  Wm_b  = (bf16*)(wp + 8 * MB);
  bf16*  Wq_b  = (bf16*)(wp + 16 * MB);
  bf16*  Wkv_b = (bf16*)(wp + 18 * MB);
  bf16*  xssm  = (bf16*)(wp + 19 * MB);
  bf16*  u     = (bf16*)(wp + 35 * MB);
  bf16*  gate  = (bf16*)(wp + 51 * MB);
  bf16*  qraw  = (bf16*)(wp + 67 * MB);
  bf16*  kvraw = (bf16*)(wp + 75 * MB);
  bf16*  dltb  = (bf16*)(wp + 79 * MB);
  // reused regions
  bf16*  qn    = (bf16*)(wp + 0 * MB);
  bf16*  kn    = (bf16*)(wp + 8 * MB);
  bf16*  vtb   = (bf16*)(wp + 10 * MB);
  bf16*  Wxp_b = (bf16*)(wp + 12 * MB);
  bf16*  Wdt_b = (bf16*)(wp + 12 * MB + 512 * 1024);
  bf16*  prm   = (bf16*)(wp + 13 * MB);
  bf16*  Wp_b  = (bf16*)(wp + 14 * MB);
  bf16*  attnb = (bf16*)(wp + 67 * MB);
  bf16*  Wmo_b = (bf16*)(wp + 75 * MB);
  bf16*  ybuf  = (bf16*)(wp + 19 * MB);
  bf16*  mam   = (bf16*)(wp + 51 * MB);
  bf16*  mrg   = (bf16*)(wp + 59 * MB);
  (void)ws_size; (void)in_sizes; (void)n_in; (void)out_size;

  auto cast = [&](const float* src, bf16* dst, int n) {
    const int n4 = n >> 2;
    cast_f2b<<<dim3((n4 + 255) / 256), 256, 0, stream>>>(src, dst, n4);
  };
  // stage 1: casts needed for input GEMMs
  cast(x_f,   xb,    T_ * 1024);
  cast(Wm_f,  Wm_b,  4096 * 1024);
  cast(Wq_f,  Wq_b,  1024 * 1024);
  cast(Wkv_f, Wkv_b, 512 * 1024);

  // stage 2: input projections
  gemm_nt<1><<<dim3(32, 16), 256, 0, stream>>>(xb, 1024, Wm_b,               1024, xssm, 2048, nullptr, T_, 2048, 1024);
  gemm_nt<1><<<dim3(32, 16), 256, 0, stream>>>(xb, 1024, Wm_b + 2048 * 1024, 1024, gate, 2048, nullptr, T_, 2048, 1024);
  gemm_nt<1><<<dim3(32, 8),  256, 0, stream>>>(xb, 1024, Wq_b,  1024, qraw,  1024, nullptr, T_, 1024, 1024);
  gemm_nt<1><<<dim3(32, 4),  256, 0, stream>>>(xb, 1024, Wkv_b, 1024, kvraw,  512, nullptr, T_,  512, 1024);

  // stage 3: qkv transform
  qkv_prep<<<dim3((T_ * 24) / 4), 256, 0, stream>>>(qraw, kvraw, q_gain, qn, kn, vtb);
  // stage 4: conv
  conv_silu<<<dim3(8, 4096), 256, 0, stream>>>(xssm, conv_w, conv_b, u);
  // stage 5: attention
  attn_fwd<<<dim3(32, 16, 2), 256, 0, stream>>>(qn, kn, vtb, attnb);

  // stage 6: remaining weight casts into freed regions
  cast(Wxp_f, Wxp_b, 96 * 2048);
  cast(Wdt_f, Wdt_b, 2048 * 64);
  cast(Wmo_f, Wmo_b, 1024 * 2048);
  cast(Wp_f,  Wp_b,  1024 * 1024);

  // stage 7: mamba tail
  gemm_nt<1><<<dim3(32, 1),  256, 0, stream>>>(u, 2048, Wxp_b, 2048, prm, 96, nullptr, T_, 96, 2048);
  gemm_nt<3><<<dim3(32, 16), 256, 0, stream>>>(prm, 96, Wdt_b, 64, dltb, 2048, b_dt, T_, 2048, 64);
  ssm_scan<<<dim3(4096), 256, 0, stream>>>(dltb, u, prm, A_log, Dv, gate, ybuf);
  gemm_nt<1><<<dim3(32, 8),  256, 0, stream>>>(ybuf, 2048, Wmo_b, 2048, mam, 1024, nullptr, T_, 1024, 2048);

  // stage 8: merge + output projection (output f32)
  merge_k<<<dim3(16384), 256, 0, stream>>>(attnb, mam, malpha, mrg);
  gemm_nt<0><<<dim3(32, 8),  256, 0, stream>>>(mrg, 1024, Wp_b, 1024, (float*)d_out, 1024, nullptr, T_, 1024, 1024);
}

// Round 6
// 925.553 us; speedup vs baseline: 2.3499x; 1.1298x over previous
//
#include <hip/hip_runtime.h>
#include <hip/hip_bf16.h>

#define B_   2
#define S_   2048
#define T_   4096
#define DIM_ 1024
#define H_   16
#define KVH_ 4
#define HD_  64
#define I_   2048
#define N_   16
#define DTR_ 64
#define MB   ((size_t)1 << 20)

typedef __hip_bfloat16 bf16;
typedef __attribute__((ext_vector_type(8))) short short8;   // 8 bf16 (4 VGPRs)
typedef __attribute__((ext_vector_type(4))) short short4v;
typedef __attribute__((ext_vector_type(4))) float f32x4;

__device__ __forceinline__ float b2f(bf16 v){ return __bfloat162float(v); }
__device__ __forceinline__ bf16  f2b(float v){ return __float2bfloat16(v); }
__device__ __forceinline__ float s2f(short s){
  return __builtin_bit_cast(float, ((unsigned int)(unsigned short)s) << 16);
}
__device__ __forceinline__ short f2s(float v){
  return (short)__builtin_bit_cast(unsigned short, f2b(v));
}

__device__ __forceinline__ void async16(const void* g, void* l) {
  __builtin_amdgcn_global_load_lds((__attribute__((address_space(1))) void*)g,
                                   (__attribute__((address_space(3))) void*)l, 16, 0, 0);
}

// ---------------------------------------------------------------------------
// f32 -> bf16 cast, 4 elements/thread
// ---------------------------------------------------------------------------
__global__ __launch_bounds__(256)
void cast_f2b(const float* __restrict__ in, bf16* __restrict__ out, int n4)
{
  const int i = blockIdx.x * 256 + threadIdx.x;
  if (i >= n4) return;
  const float4 v = ((const float4*)in)[i];
  short4v o;
  o.x = f2s(v.x); o.y = f2s(v.y); o.z = f2s(v.z); o.w = f2s(v.w);
  *(short4v*)(out + (size_t)i * 4) = o;
}

// ---------------------------------------------------------------------------
// NT GEMM: C[M,N] = A[M,K] (row-major) * W[N,K]^T (row-major)
// MODE 0: f32   MODE 1: bf16   MODE 2: bf16 softplus(v+bias[col])
// TS 0: normal store   TS 1: transposed store Ct[col][row] (bf16)   TS 2: both
// Transposed store: 4 consecutive rows per (quad) -> one 8B store, so a block
// writes full 256B segments of each Ct row => no HBM write amplification.
// ---------------------------------------------------------------------------
template<int MODE, int TS>
__global__ __launch_bounds__(256)
void gemm_nt(const bf16* __restrict__ A, int lda,
             const bf16* __restrict__ W, int ldw,
             void* __restrict__ C, int ldc,
             bf16* __restrict__ Ct, int ldt,
             const float* __restrict__ bias,
             int M, int N, int K)
{
  __shared__ __align__(16) bf16 As[128*32];
  __shared__ __align__(16) bf16 Bs[128*32];
  const int tid  = threadIdx.x;
  const int lane = tid & 63;
  const int wave = tid >> 6;
  const int l16  = lane & 15;
  const int quad = lane >> 4;
  const int wm   = (wave >> 1) << 6;
  const int wn   = (wave & 1) << 6;
  const int m0   = blockIdx.x << 7;
  const int n0   = blockIdx.y << 7;

  f32x4 acc[4][4];
  const f32x4 zero = {0.f, 0.f, 0.f, 0.f};
  #pragma unroll
  for (int i = 0; i < 4; i++)
    #pragma unroll
    for (int j = 0; j < 4; j++) acc[i][j] = zero;

  for (int k0 = 0; k0 < K; k0 += 32) {
    #pragma unroll
    for (int p = 0; p < 2; p++) {
      const int linear = ((p << 8) + tid) << 4;   // byte offset in 8KB tile
      const int row    = linear >> 6;             // 64 B per row (32 bf16)
      const int inrow  = linear & 63;
      async16(A + (size_t)(m0 + row) * lda + k0 + (inrow >> 1), (char*)As + linear);
      int wr = n0 + row; if (wr > N - 1) wr = N - 1;   // clamp for N=96
      async16(W + (size_t)wr * ldw + k0 + (inrow >> 1), (char*)Bs + linear);
    }
    __syncthreads();
    short8 af[4], bfr[4];
    #pragma unroll
    for (int mt = 0; mt < 4; mt++)
      af[mt] = *(const short8*)((const char*)As + ((wm + (mt << 4) + l16) << 6) + (quad << 4));
    #pragma unroll
    for (int nt = 0; nt < 4; nt++)
      bfr[nt] = *(const short8*)((const char*)Bs + ((wn + (nt << 4) + l16) << 6) + (quad << 4));
    #pragma unroll
    for (int mt = 0; mt < 4; mt++)
      #pragma unroll
      for (int nt = 0; nt < 4; nt++)
        acc[mt][nt] = __builtin_amdgcn_mfma_f32_16x16x32_bf16(af[mt], bfr[nt], acc[mt][nt], 0, 0, 0);
    __syncthreads();
  }

  #pragma unroll
  for (int mt = 0; mt < 4; mt++) {
    #pragma unroll
    for (int nt = 0; nt < 4; nt++) {
      const int col = n0 + wn + (nt << 4) + l16;
      if (col >= N) continue;
      const int rowbase = m0 + wm + (mt << 4) + (quad << 2);
      float v[4];
      #pragma unroll
      for (int r = 0; r < 4; r++) {
        float t = acc[mt][nt][r];
        if (MODE == 2) {
          t += bias[col];
          t = (t > 20.f) ? t : log1pf(__expf(t));
        }
        v[r] = t;
      }
      if (TS == 0 || TS == 2) {
        #pragma unroll
        for (int r = 0; r < 4; r++) {
          if (MODE == 0) ((float*)C)[(size_t)(rowbase + r) * ldc + col] = v[r];
          else           ((bf16*)C)[(size_t)(rowbase + r) * ldc + col] = f2b(v[r]);
        }
      }
      if (TS >= 1) {
        short4v p;
        #pragma unroll
        for (int r = 0; r < 4; r++) p[r] = f2s(v[r]);
        *(short4v*)(Ct + (size_t)col * ldt + rowbase) = p;
      }
    }
  }
}

// ---------------------------------------------------------------------------
// QKV prep: RMSNorm(q,k) + RoPE(q,k) + q_gain, layout transforms.
// ---------------------------------------------------------------------------
__global__ __launch_bounds__(256)
void qkv_prep(const bf16* __restrict__ qraw, const bf16* __restrict__ kvraw,
              const float* __restrict__ q_gain,
              bf16* __restrict__ qn, bf16* __restrict__ kn, bf16* __restrict__ vt)
{
  const int wid  = blockIdx.x * 4 + (threadIdx.x >> 6);
  const int lane = threadIdx.x & 63;
  const int t    = wid / 24;
  const int slot = wid % 24;
  const int b = t >> 11, s = t & 2047;

  float val;
  if (slot < 16)       val = b2f(qraw [(size_t)t * 1024 + slot * 64 + lane]);
  else if (slot < 20)  val = b2f(kvraw[(size_t)t * 512  + (slot - 16) * 64 + lane]);
  else                 val = b2f(kvraw[(size_t)t * 512  + 256 + (slot - 20) * 64 + lane]);

  if (slot < 20) {
    float ss = val * val;
    #pragma unroll
    for (int off = 32; off; off >>= 1) ss += __shfl_xor(ss, off);
    val *= rsqrtf(ss * (1.0f / 64.0f) + 1.1920929e-07f);
    const int j = lane & 31;
    const float x1 = __shfl(val, j);
    const float x2 = __shfl(val, j + 32);
    const float inv = powf(10000.0f, -(float)j * (1.0f / 32.0f));
    const float ang = (float)s * inv;
    const float c = cosf(ang), sn = sinf(ang);
    val = (lane < 32) ? (x1 * c + x2 * sn) : (x2 * c - x1 * sn);
  }
  if (slot < 16) {
    val *= q_gain[slot];
    qn[((size_t)(b * 16 + slot) * 2048 + s) * 64 + lane] = f2b(val);
  } else if (slot < 20) {
    kn[((size_t)(b * 4 + (slot - 16)) * 2048 + s) * 64 + lane] = f2b(val);
  } else {
    vt[((size_t)(b * 4 + (slot - 20)) * 64 + lane) * 2048 + s] = f2b(val);
  }
}

// ---------------------------------------------------------------------------
// Flash attention (causal, GQA 16->4). Block = (b, h, 64 q-rows); 4 waves.
// ---------------------------------------------------------------------------
__global__ __launch_bounds__(256)
void attn_fwd(const bf16* __restrict__ qn, const bf16* __restrict__ kn,
              const bf16* __restrict__ vt, bf16* __restrict__ attn)
{
  __shared__ __align__(16) bf16 Plds[4][16][32];
  const int b = blockIdx.z, h = blockIdx.y, q0 = blockIdx.x * 64;
  const int wave = threadIdx.x >> 6, lane = threadIdx.x & 63;
  const int l16 = lane & 15, quad = lane >> 4;
  const int kvh = h >> 2;
  const bf16* Q  = qn + (size_t)(b * 16 + h)   * 2048 * 64;
  const bf16* Kp = kn + (size_t)(b * 4 + kvh)  * 2048 * 64;
  const bf16* Vt = vt + (size_t)(b * 4 + kvh)  * 64 * 2048;

  const int qrow_l = q0 + wave * 16 + l16;
  const short8 qf0 = *(const short8*)(Q + (size_t)qrow_l * 64 + quad * 8);
  const short8 qf1 = *(const short8*)(Q + (size_t)qrow_l * 64 + 32 + quad * 8);

  f32x4 acc[4];
  const f32x4 zero = {0.f, 0.f, 0.f, 0.f};
  #pragma unroll
  for (int i = 0; i < 4; i++) acc[i] = zero;
  float m_r[4], l_r[4];
  #pragma unroll
  for (int r = 0; r < 4; r++) { m_r[r] = -1e30f; l_r[r] = 0.f; }

  const int nkt = (q0 + 64) >> 5;
  for (int kt = 0; kt < nkt; kt++) {
    const int kb = kt << 5;
    const short8 kfA0 = *(const short8*)(Kp + (size_t)(kb + l16) * 64 + quad * 8);
    const short8 kfA1 = *(const short8*)(Kp + (size_t)(kb + l16) * 64 + 32 + quad * 8);
    const short8 kfB0 = *(const short8*)(Kp + (size_t)(kb + 16 + l16) * 64 + quad * 8);
    const short8 kfB1 = *(const short8*)(Kp + (size_t)(kb + 16 + l16) * 64 + 32 + quad * 8);
    f32x4 sA = zero, sB = zero;
    sA = __builtin_amdgcn_mfma_f32_16x16x32_bf16(qf0, kfA0, sA, 0, 0, 0);
    sA = __builtin_amdgcn_mfma_f32_16x16x32_bf16(qf1, kfA1, sA, 0, 0, 0);
    sB = __builtin_amdgcn_mfma_f32_16x16x32_bf16(qf0, kfB0, sB, 0, 0, 0);
    sB = __builtin_amdgcn_mfma_f32_16x16x32_bf16(qf1, kfB1, sB, 0, 0, 0);

    const int colA = kb + l16, colB = kb + 16 + l16;
    float pA[4], pB[4], alpha[4];
    #pragma unroll
    for (int r = 0; r < 4; r++) {
      const int row = q0 + wave * 16 + quad * 4 + r;
      float a  = sA[r] * 0.125f;
      float bb = sB[r] * 0.125f;
      if (colA > row) a  = -1e30f;
      if (colB > row) bb = -1e30f;
      float tm = fmaxf(a, bb);
      #pragma unroll
      for (int off = 8; off; off >>= 1) tm = fmaxf(tm, __shfl_xor(tm, off));
      const float nm = fmaxf(m_r[r], tm);
      alpha[r] = __expf(m_r[r] - nm);
      m_r[r] = nm;
      const float pa = __expf(a - nm), pb = __expf(bb - nm);
      pA[r] = pa; pB[r] = pb;
      float ps = pa + pb;
      #pragma unroll
      for (int off = 8; off; off >>= 1) ps += __shfl_xor(ps, off);
      l_r[r] = l_r[r] * alpha[r] + ps;
    }
    #pragma unroll
    for (int nt = 0; nt < 4; nt++)
      #pragma unroll
      for (int r = 0; r < 4; r++) acc[nt][r] *= alpha[r];

    __syncthreads();
    #pragma unroll
    for (int r = 0; r < 4; r++) {
      Plds[wave][quad * 4 + r][l16]      = f2b(pA[r]);
      Plds[wave][quad * 4 + r][16 + l16] = f2b(pB[r]);
    }
    __syncthreads();
    const short8 pf = *(const short8*)(&Plds[wave][l16][quad * 8]);
    #pragma unroll
    for (int nt = 0; nt < 4; nt++) {
      const short8 vf = *(const short8*)(Vt + (size_t)(nt * 16 + l16) * 2048 + kb + quad * 8);
      acc[nt] = __builtin_amdgcn_mfma_f32_16x16x32_bf16(pf, vf, acc[nt], 0, 0, 0);
    }
  }

  #pragma unroll
  for (int nt = 0; nt < 4; nt++)
    #pragma unroll
    for (int r = 0; r < 4; r++) {
      const int row = q0 + wave * 16 + quad * 4 + r;
      attn[((size_t)b * 2048 + row) * 1024 + h * 64 + nt * 16 + l16] = f2b(acc[nt][r] / l_r[r]);
    }
}

// ---------------------------------------------------------------------------
// Depthwise causal conv (K=4) + bias + SiLU, channel-major input.
// grid (2048 channels, 16 token-slabs), 256 threads = tokens.
// Reads xssmT[i][t] contiguous; writes uT[i][t] (contig) and u[t][i] (L2-merged).
// ---------------------------------------------------------------------------
__global__ __launch_bounds__(256)
void conv_silu_t(const bf16* __restrict__ xssmT, const float* __restrict__ cw,
                 const float* __restrict__ cb,
                 bf16* __restrict__ u, bf16* __restrict__ uT)
{
  const int i = blockIdx.x;
  const int t = blockIdx.y * 256 + threadIdx.x;
  const int s = t & 2047;
  float acc = cb[i];
  #pragma unroll
  for (int kk = 0; kk < 4; kk++) {
    if (s - 3 + kk >= 0)
      acc += s2f(__builtin_bit_cast(short, xssmT[(size_t)i * 4096 + t - 3 + kk])) * cw[i * 4 + kk];
  }
  const float sig = 1.f / (1.f + __expf(-acc));
  const bf16 r = f2b(acc * sig);
  u [(size_t)t * 2048 + i] = r;
  uT[(size_t)i * 4096 + t] = r;
}

// ---------------------------------------------------------------------------
// bf16 transpose: in[R][C] -> out[C][R]. 64x64 LDS tiles, 256 threads.
// ---------------------------------------------------------------------------
__global__ __launch_bounds__(256)
void transpose_bf16(const bf16* __restrict__ in, bf16* __restrict__ out,
                    int R, int C)
{
  __shared__ bf16 tile[64][65];
  const int c0 = blockIdx.x * 64, r0 = blockIdx.y * 64;
  #pragma unroll
  for (int it = 0; it < 2; it++) {
    const int linear = (it * 256 + threadIdx.x) * 8;
    const int r = linear >> 6, cc = linear & 63;
    const short8 v = *(const short8*)(in + (size_t)(r0 + r) * C + c0 + cc);
    #pragma unroll
    for (int k = 0; k < 8; k++)
      tile[r][cc + k] = __builtin_bit_cast(bf16, (unsigned short)v[k]);
  }
  __syncthreads();
  #pragma unroll
  for (int it = 0; it < 2; it++) {
    const int linear = (it * 256 + threadIdx.x) * 8;
    const int oc = linear >> 6, k = linear & 63;
    short8 v;
    #pragma unroll
    for (int kk = 0; kk < 8; kk++)
      v[kk] = (short)__builtin_bit_cast(unsigned short, tile[k + kk][oc]);
    *(short8*)(out + (size_t)(c0 + oc) * R + r0 + k) = v;
  }
}

// ---------------------------------------------------------------------------
// Chunked two-pass selective scan, channel-major I/O. One block per (b,i);
// 256 threads = 16 n x 16 chunks of 128. All streams contiguous in t,
// vectorized short8 every 8 steps.
// ---------------------------------------------------------------------------
__global__ __launch_bounds__(256)
void ssm_scan(const bf16* __restrict__ dltT, const bf16* __restrict__ uT,
              const bf16* __restrict__ prmT, const float* __restrict__ A_log,
              const float* __restrict__ Dv, const bf16* __restrict__ gateT,
              bf16* __restrict__ youtT)
{
  __shared__ float Pl[16][17], Fl[16][17], Il[16][17];
  const int blk = blockIdx.x;          // b*2048 + i
  const int b = blk >> 11, i = blk & 2047;
  const int n = threadIdx.x & 15, c = threadIdx.x >> 4;
  const float a  = -__expf(A_log[i * 16 + n]);
  const float Di = Dv[i];
  const size_t rowoff = (size_t)b * 2048 + c * 128;
  const bf16* dp = dltT  + (size_t)i * 4096 + rowoff;
  const bf16* up = uT    + (size_t)i * 4096 + rowoff;
  const bf16* Bp = prmT  + (size_t)(64 + n) * 4096 + rowoff;
  const bf16* Cp = prmT  + (size_t)(80 + n) * 4096 + rowoff;
  const bf16* gp = gateT + (size_t)i * 4096 + rowoff;
  bf16*       yp = youtT + (size_t)i * 4096 + rowoff;

  // pass 1: local scan from zero -> decay product P, final state F
  float P = 1.f, F = 0.f;
  for (int j0 = 0; j0 < 128; j0 += 8) {
    const short8 d8 = *(const short8*)(dp + j0);
    const short8 u8 = *(const short8*)(up + j0);
    const short8 B8 = *(const short8*)(Bp + j0);
    #pragma unroll
    for (int j = 0; j < 8; j++) {
      const float dt = s2f(d8[j]);
      const float dA = __expf(dt * a);
      P *= dA;
      F = F * dA + dt * s2f(u8[j]) * s2f(B8[j]);
    }
  }
  Pl[n][c] = P; Fl[n][c] = F;
  __syncthreads();

  // combine: serial over 16 chunks, one thread per n
  if (threadIdx.x < 16) {
    const int nn = threadIdx.x;
    float s = 0.f;
    #pragma unroll
    for (int cc = 0; cc < 16; cc++) {
      Il[nn][cc] = s;
      s = Fl[nn][cc] + Pl[nn][cc] * s;
    }
  }
  __syncthreads();

  // pass 2: replay from exact init, emit y
  float state = Il[n][c];
  for (int j0 = 0; j0 < 128; j0 += 8) {
    const short8 d8 = *(const short8*)(dp + j0);
    const short8 u8 = *(const short8*)(up + j0);
    const short8 B8 = *(const short8*)(Bp + j0);
    const short8 C8 = *(const short8*)(Cp + j0);
    const short8 g8 = *(const short8*)(gp + j0);
    short8 o8;
    #pragma unroll
    for (int j = 0; j < 8; j++) {
      const float dt = s2f(d8[j]);
      const float ut = s2f(u8[j]);
      const float dA = __expf(dt * a);
      state = state * dA + dt * ut * s2f(B8[j]);
      float y = state * s2f(C8[j]);
      y += __shfl_xor(y, 1); y += __shfl_xor(y, 2);
      y += __shfl_xor(y, 4); y += __shfl_xor(y, 8);
      const float g  = s2f(g8[j]);
      const float gs = g / (1.f + __expf(-g));
      o8[j] = f2s((y + ut * Di) * gs);
    }
    if (n == 0) *(short8*)(yp + j0) = o8;
  }
}

// ---------------------------------------------------------------------------
__global__ __launch_bounds__(256)
void merge_k(const bf16* __restrict__ attn, const bf16* __restrict__ mamba,
             const float* __restrict__ malpha, bf16* __restrict__ merged)
{
  const size_t idx = (size_t)blockIdx.x * 256 + threadIdx.x;
  const float al = 1.f / (1.f + __expf(-malpha[0]));
  merged[idx] = f2b(al * b2f(attn[idx]) + (1.f - al) * b2f(mamba[idx]));
}

// ---------------------------------------------------------------------------
extern "C" void kernel_launch(void* const* d_in, const int* in_sizes, int n_in,
                              void* d_out, int out_size, void* d_ws, size_t ws_size,
                              hipStream_t stream)
{
  const float* x_f     = (const float*)d_in[0];
  const float* Wm_f    = (const float*)d_in[1];
  const float* Wq_f    = (const float*)d_in[2];
  const float* Wkv_f   = (const float*)d_in[3];
  const float* q_gain  = (const float*)d_in[4];
  const float* conv_w  = (const float*)d_in[5];
  const float* conv_b  = (const float*)d_in[6];
  const float* Wxp_f   = (const float*)d_in[7];
  const float* Wdt_f   = (const float*)d_in[8];
  const float* b_dt    = (const float*)d_in[9];
  const float* A_log   = (const float*)d_in[10];
  const float* Dv      = (const float*)d_in[11];
  const float* Wmo_f   = (const float*)d_in[12];
  const float* Wp_f    = (const float*)d_in[13];
  const float* malpha  = (const float*)d_in[14];

  // Static arena, peak 111 MB. Lifetimes:
  //  [0,8)    xb -> qn            [8,16)  Wm_b -> kn,vtb,Wxp,Wdt,prm,prmT
  //  [16,18)  Wq_b -> Wp_b        [18,19) Wkv_b
  //  [19,35)  xssmT -> ybuf       [35,51) gateT -> mam(35-43), mrg(43-51)
  //  [51,67)  u -> ybufT          [67,83) uT
  //  [83,91)  qraw -> attnb       [91,95) kvraw -> Wmo_b
  //  [95,111) dltT
  char* wp = (char*)d_ws;
  bf16*  xb    = (bf16*)(wp + 0 * MB);
  bf16*  Wm_b  = (bf16*)(wp + 8 * MB);
  bf16*  Wq_b  = (bf16*)(wp + 16 * MB);
  bf16*  Wkv_b = (bf16*)(wp + 18 * MB);
  bf16*  xssmT = (bf16*)(wp + 19 * MB);
  bf16*  gateT = (bf16*)(wp + 35 * MB);
  bf16*  u     = (bf16*)(wp + 51 * MB);
  bf16*  uT    = (bf16*)(wp + 67 * MB);
  bf16*  qraw  = (bf16*)(wp + 83 * MB);
  bf16*  kvraw = (bf16*)(wp + 91 * MB);
  bf16*  dltT  = (bf16*)(wp + 95 * MB);
  // reused regions
  bf16*  qn    = (bf16*)(wp + 0 * MB);
  bf16*  kn    = (bf16*)(wp + 8 * MB);
  bf16*  vtb   = (bf16*)(wp + 10 * MB);
  bf16*  Wxp_b = (bf16*)(wp + 12 * MB);
  bf16*  Wdt_b = (bf16*)(wp + 12 * MB + 512 * 1024);
  bf16*  prm   = (bf16*)(wp + 13 * MB);
  bf16*  prmT  = (bf16*)(wp + 13 * MB + 768 * 1024);
  bf16*  Wp_b  = (bf16*)(wp + 16 * MB);
  bf16*  attnb = (bf16*)(wp + 83 * MB);
  bf16*  Wmo_b = (bf16*)(wp + 91 * MB);
  bf16*  ybuf  = (bf16*)(wp + 19 * MB);
  bf16*  ybufT = (bf16*)(wp + 51 * MB);
  bf16*  mam   = (bf16*)(wp + 35 * MB);
  bf16*  mrg   = (bf16*)(wp + 43 * MB);
  (void)ws_size; (void)in_sizes; (void)n_in; (void)out_size;

  auto cast = [&](const float* src, bf16* dst, int n) {
    const int n4 = n >> 2;
    cast_f2b<<<dim3((n4 + 255) / 256), 256, 0, stream>>>(src, dst, n4);
  };
  cast(x_f,   xb,    T_ * 1024);
  cast(Wm_f,  Wm_b,  4096 * 1024);
  cast(Wq_f,  Wq_b,  1024 * 1024);
  cast(Wkv_f, Wkv_b, 512 * 1024);

  // input projections: xssm/gate/delta-side outputs stored channel-major
  gemm_nt<1,1><<<dim3(32, 16), 256, 0, stream>>>(xb, 1024, Wm_b,               1024, nullptr, 0, xssmT, 4096, nullptr, T_, 2048, 1024);
  gemm_nt<1,1><<<dim3(32, 16), 256, 0, stream>>>(xb, 1024, Wm_b + 2048 * 1024, 1024, nullptr, 0, gateT, 4096, nullptr, T_, 2048, 1024);
  gemm_nt<1,0><<<dim3(32, 8),  256, 0, stream>>>(xb, 1024, Wq_b,  1024, qraw,  1024, nullptr, 0, nullptr, T_, 1024, 1024);
  gemm_nt<1,0><<<dim3(32, 4),  256, 0, stream>>>(xb, 1024, Wkv_b, 1024, kvraw,  512, nullptr, 0, nullptr, T_,  512, 1024);

  qkv_prep<<<dim3((T_ * 24) / 4), 256, 0, stream>>>(qraw, kvraw, q_gain, qn, kn, vtb);
  conv_silu_t<<<dim3(2048, 16), 256, 0, stream>>>(xssmT, conv_w, conv_b, u, uT);
  attn_fwd<<<dim3(32, 16, 2), 256, 0, stream>>>(qn, kn, vtb, attnb);

  cast(Wxp_f, Wxp_b, 96 * 2048);
  cast(Wdt_f, Wdt_b, 2048 * 64);
  cast(Wmo_f, Wmo_b, 1024 * 2048);
  cast(Wp_f,  Wp_b,  1024 * 1024);

  // mamba tail: params dual-stored; delta channel-major
  gemm_nt<1,2><<<dim3(32, 1),  256, 0, stream>>>(u, 2048, Wxp_b, 2048, prm, 96, prmT, 4096, nullptr, T_, 96, 2048);
  gemm_nt<2,1><<<dim3(32, 16), 256, 0, stream>>>(prm, 96, Wdt_b, 64, nullptr, 0, dltT, 4096, b_dt, T_, 2048, 64);
  ssm_scan<<<dim3(4096), 256, 0, stream>>>(dltT, uT, prmT, A_log, Dv, gateT, ybufT);
  transpose_bf16<<<dim3(64, 32), 256, 0, stream>>>(ybufT, ybuf, 2048, 4096);
  gemm_nt<1,0><<<dim3(32, 8),  256, 0, stream>>>(ybuf, 2048, Wmo_b, 2048, mam, 1024, nullptr, 0, nullptr, T_, 1024, 2048);

  merge_k<<<dim3(16384), 256, 0, stream>>>(attnb, mam, malpha, mrg);
  gemm_nt<0,0><<<dim3(32, 8),  256, 0, stream>>>(mrg, 1024, Wp_b, 1024, (float*)d_out, 1024, nullptr, 0, nullptr, T_, 1024, 1024);
}

// Round 7
// 903.937 us; speedup vs baseline: 2.4061x; 1.0239x over previous
//
#include <hip/hip_runtime.h>
#include <hip/hip_bf16.h>

#define B_   2
#define S_   2048
#define T_   4096
#define DIM_ 1024
#define H_   16
#define KVH_ 4
#define HD_  64
#define I_   2048
#define N_   16
#define DTR_ 64
#define MB   ((size_t)1 << 20)

typedef __hip_bfloat16 bf16;
typedef __attribute__((ext_vector_type(8))) short short8;   // 8 bf16 (4 VGPRs)
typedef __attribute__((ext_vector_type(4))) short short4v;
typedef __attribute__((ext_vector_type(4))) float f32x4;

__device__ __forceinline__ float b2f(bf16 v){ return __bfloat162float(v); }
__device__ __forceinline__ bf16  f2b(float v){ return __float2bfloat16(v); }
__device__ __forceinline__ float s2f(short s){
  return __builtin_bit_cast(float, ((unsigned int)(unsigned short)s) << 16);
}
__device__ __forceinline__ short f2s(float v){
  return (short)__builtin_bit_cast(unsigned short, f2b(v));
}

__device__ __forceinline__ void async16(const void* g, void* l) {
  __builtin_amdgcn_global_load_lds((__attribute__((address_space(1))) void*)g,
                                   (__attribute__((address_space(3))) void*)l, 16, 0, 0);
}

// ---------------------------------------------------------------------------
// f32 -> bf16 cast, 4 elements/thread
// ---------------------------------------------------------------------------
__global__ __launch_bounds__(256)
void cast_f2b(const float* __restrict__ in, bf16* __restrict__ out, int n4)
{
  const int i = blockIdx.x * 256 + threadIdx.x;
  if (i >= n4) return;
  const float4 v = ((const float4*)in)[i];
  short4v o;
  o.x = f2s(v.x); o.y = f2s(v.y); o.z = f2s(v.z); o.w = f2s(v.w);
  *(short4v*)(out + (size_t)i * 4) = o;
}

// ---------------------------------------------------------------------------
// NT GEMM: C[M,N] = A[M,K] (row-major) * W[N,K]^T (row-major)
// MODE 0: f32   MODE 1: bf16   MODE 2: bf16 softplus(v+bias[col])
// TS 0: normal store   TS 1: transposed store Ct[col][row] (bf16)   TS 2: both
// ---------------------------------------------------------------------------
template<int MODE, int TS>
__global__ __launch_bounds__(256)
void gemm_nt(const bf16* __restrict__ A, int lda,
             const bf16* __restrict__ W, int ldw,
             void* __restrict__ C, int ldc,
             bf16* __restrict__ Ct, int ldt,
             const float* __restrict__ bias,
             int M, int N, int K)
{
  __shared__ __align__(16) bf16 As[128*32];
  __shared__ __align__(16) bf16 Bs[128*32];
  const int tid  = threadIdx.x;
  const int lane = tid & 63;
  const int wave = tid >> 6;
  const int l16  = lane & 15;
  const int quad = lane >> 4;
  const int wm   = (wave >> 1) << 6;
  const int wn   = (wave & 1) << 6;
  const int m0   = blockIdx.x << 7;
  const int n0   = blockIdx.y << 7;

  f32x4 acc[4][4];
  const f32x4 zero = {0.f, 0.f, 0.f, 0.f};
  #pragma unroll
  for (int i = 0; i < 4; i++)
    #pragma unroll
    for (int j = 0; j < 4; j++) acc[i][j] = zero;

  for (int k0 = 0; k0 < K; k0 += 32) {
    #pragma unroll
    for (int p = 0; p < 2; p++) {
      const int linear = ((p << 8) + tid) << 4;   // byte offset in 8KB tile
      const int row    = linear >> 6;             // 64 B per row (32 bf16)
      const int inrow  = linear & 63;
      async16(A + (size_t)(m0 + row) * lda + k0 + (inrow >> 1), (char*)As + linear);
      int wr = n0 + row; if (wr > N - 1) wr = N - 1;   // clamp for N=96
      async16(W + (size_t)wr * ldw + k0 + (inrow >> 1), (char*)Bs + linear);
    }
    __syncthreads();
    short8 af[4], bfr[4];
    #pragma unroll
    for (int mt = 0; mt < 4; mt++)
      af[mt] = *(const short8*)((const char*)As + ((wm + (mt << 4) + l16) << 6) + (quad << 4));
    #pragma unroll
    for (int nt = 0; nt < 4; nt++)
      bfr[nt] = *(const short8*)((const char*)Bs + ((wn + (nt << 4) + l16) << 6) + (quad << 4));
    #pragma unroll
    for (int mt = 0; mt < 4; mt++)
      #pragma unroll
      for (int nt = 0; nt < 4; nt++)
        acc[mt][nt] = __builtin_amdgcn_mfma_f32_16x16x32_bf16(af[mt], bfr[nt], acc[mt][nt], 0, 0, 0);
    __syncthreads();
  }

  #pragma unroll
  for (int mt = 0; mt < 4; mt++) {
    #pragma unroll
    for (int nt = 0; nt < 4; nt++) {
      const int col = n0 + wn + (nt << 4) + l16;
      if (col >= N) continue;
      const int rowbase = m0 + wm + (mt << 4) + (quad << 2);
      float v[4];
      #pragma unroll
      for (int r = 0; r < 4; r++) {
        float t = acc[mt][nt][r];
        if (MODE == 2) {
          t += bias[col];
          t = (t > 20.f) ? t : log1pf(__expf(t));
        }
        v[r] = t;
      }
      if (TS == 0 || TS == 2) {
        #pragma unroll
        for (int r = 0; r < 4; r++) {
          if (MODE == 0) ((float*)C)[(size_t)(rowbase + r) * ldc + col] = v[r];
          else           ((bf16*)C)[(size_t)(rowbase + r) * ldc + col] = f2b(v[r]);
        }
      }
      if (TS >= 1) {
        short4v p;
        #pragma unroll
        for (int r = 0; r < 4; r++) p[r] = f2s(v[r]);
        *(short4v*)(Ct + (size_t)col * ldt + rowbase) = p;
      }
    }
  }
}

// ---------------------------------------------------------------------------
// QKV prep: RMSNorm(q,k) + RoPE(q,k) + q_gain, layout transforms.
// ---------------------------------------------------------------------------
__global__ __launch_bounds__(256)
void qkv_prep(const bf16* __restrict__ qraw, const bf16* __restrict__ kvraw,
              const float* __restrict__ q_gain,
              bf16* __restrict__ qn, bf16* __restrict__ kn, bf16* __restrict__ vt)
{
  const int wid  = blockIdx.x * 4 + (threadIdx.x >> 6);
  const int lane = threadIdx.x & 63;
  const int t    = wid / 24;
  const int slot = wid % 24;
  const int b = t >> 11, s = t & 2047;

  float val;
  if (slot < 16)       val = b2f(qraw [(size_t)t * 1024 + slot * 64 + lane]);
  else if (slot < 20)  val = b2f(kvraw[(size_t)t * 512  + (slot - 16) * 64 + lane]);
  else                 val = b2f(kvraw[(size_t)t * 512  + 256 + (slot - 20) * 64 + lane]);

  if (slot < 20) {
    float ss = val * val;
    #pragma unroll
    for (int off = 32; off; off >>= 1) ss += __shfl_xor(ss, off);
    val *= rsqrtf(ss * (1.0f / 64.0f) + 1.1920929e-07f);
    const int j = lane & 31;
    const float x1 = __shfl(val, j);
    const float x2 = __shfl(val, j + 32);
    const float inv = powf(10000.0f, -(float)j * (1.0f / 32.0f));
    const float ang = (float)s * inv;
    const float c = cosf(ang), sn = sinf(ang);
    val = (lane < 32) ? (x1 * c + x2 * sn) : (x2 * c - x1 * sn);
  }
  if (slot < 16) {
    val *= q_gain[slot];
    qn[((size_t)(b * 16 + slot) * 2048 + s) * 64 + lane] = f2b(val);
  } else if (slot < 20) {
    kn[((size_t)(b * 4 + (slot - 16)) * 2048 + s) * 64 + lane] = f2b(val);
  } else {
    vt[((size_t)(b * 4 + (slot - 20)) * 64 + lane) * 2048 + s] = f2b(val);
  }
}

// ---------------------------------------------------------------------------
// Flash attention (causal, GQA 16->4). Block = (b, h, 64 q-rows); 4 waves.
// ---------------------------------------------------------------------------
__global__ __launch_bounds__(256)
void attn_fwd(const bf16* __restrict__ qn, const bf16* __restrict__ kn,
              const bf16* __restrict__ vt, bf16* __restrict__ attn)
{
  __shared__ __align__(16) bf16 Plds[4][16][32];
  const int b = blockIdx.z, h = blockIdx.y, q0 = blockIdx.x * 64;
  const int wave = threadIdx.x >> 6, lane = threadIdx.x & 63;
  const int l16 = lane & 15, quad = lane >> 4;
  const int kvh = h >> 2;
  const bf16* Q  = qn + (size_t)(b * 16 + h)   * 2048 * 64;
  const bf16* Kp = kn + (size_t)(b * 4 + kvh)  * 2048 * 64;
  const bf16* Vt = vt + (size_t)(b * 4 + kvh)  * 64 * 2048;

  const int qrow_l = q0 + wave * 16 + l16;
  const short8 qf0 = *(const short8*)(Q + (size_t)qrow_l * 64 + quad * 8);
  const short8 qf1 = *(const short8*)(Q + (size_t)qrow_l * 64 + 32 + quad * 8);

  f32x4 acc[4];
  const f32x4 zero = {0.f, 0.f, 0.f, 0.f};
  #pragma unroll
  for (int i = 0; i < 4; i++) acc[i] = zero;
  float m_r[4], l_r[4];
  #pragma unroll
  for (int r = 0; r < 4; r++) { m_r[r] = -1e30f; l_r[r] = 0.f; }

  const int nkt = (q0 + 64) >> 5;
  for (int kt = 0; kt < nkt; kt++) {
    const int kb = kt << 5;
    const short8 kfA0 = *(const short8*)(Kp + (size_t)(kb + l16) * 64 + quad * 8);
    const short8 kfA1 = *(const short8*)(Kp + (size_t)(kb + l16) * 64 + 32 + quad * 8);
    const short8 kfB0 = *(const short8*)(Kp + (size_t)(kb + 16 + l16) * 64 + quad * 8);
    const short8 kfB1 = *(const short8*)(Kp + (size_t)(kb + 16 + l16) * 64 + 32 + quad * 8);
    f32x4 sA = zero, sB = zero;
    sA = __builtin_amdgcn_mfma_f32_16x16x32_bf16(qf0, kfA0, sA, 0, 0, 0);
    sA = __builtin_amdgcn_mfma_f32_16x16x32_bf16(qf1, kfA1, sA, 0, 0, 0);
    sB = __builtin_amdgcn_mfma_f32_16x16x32_bf16(qf0, kfB0, sB, 0, 0, 0);
    sB = __builtin_amdgcn_mfma_f32_16x16x32_bf16(qf1, kfB1, sB, 0, 0, 0);

    const int colA = kb + l16, colB = kb + 16 + l16;
    float pA[4], pB[4], alpha[4];
    #pragma unroll
    for (int r = 0; r < 4; r++) {
      const int row = q0 + wave * 16 + quad * 4 + r;
      float a  = sA[r] * 0.125f;
      float bb = sB[r] * 0.125f;
      if (colA > row) a  = -1e30f;
      if (colB > row) bb = -1e30f;
      float tm = fmaxf(a, bb);
      #pragma unroll
      for (int off = 8; off; off >>= 1) tm = fmaxf(tm, __shfl_xor(tm, off));
      const float nm = fmaxf(m_r[r], tm);
      alpha[r] = __expf(m_r[r] - nm);
      m_r[r] = nm;
      const float pa = __expf(a - nm), pb = __expf(bb - nm);
      pA[r] = pa; pB[r] = pb;
      float ps = pa + pb;
      #pragma unroll
      for (int off = 8; off; off >>= 1) ps += __shfl_xor(ps, off);
      l_r[r] = l_r[r] * alpha[r] + ps;
    }
    #pragma unroll
    for (int nt = 0; nt < 4; nt++)
      #pragma unroll
      for (int r = 0; r < 4; r++) acc[nt][r] *= alpha[r];

    __syncthreads();
    #pragma unroll
    for (int r = 0; r < 4; r++) {
      Plds[wave][quad * 4 + r][l16]      = f2b(pA[r]);
      Plds[wave][quad * 4 + r][16 + l16] = f2b(pB[r]);
    }
    __syncthreads();
    const short8 pf = *(const short8*)(&Plds[wave][l16][quad * 8]);
    #pragma unroll
    for (int nt = 0; nt < 4; nt++) {
      const short8 vf = *(const short8*)(Vt + (size_t)(nt * 16 + l16) * 2048 + kb + quad * 8);
      acc[nt] = __builtin_amdgcn_mfma_f32_16x16x32_bf16(pf, vf, acc[nt], 0, 0, 0);
    }
  }

  #pragma unroll
  for (int nt = 0; nt < 4; nt++)
    #pragma unroll
    for (int r = 0; r < 4; r++) {
      const int row = q0 + wave * 16 + quad * 4 + r;
      attn[((size_t)b * 2048 + row) * 1024 + h * 64 + nt * 16 + l16] = f2b(acc[nt][r] / l_r[r]);
    }
}

// ---------------------------------------------------------------------------
// Depthwise causal conv (K=4) + bias + SiLU, channel-major in/out only.
// (Token-major u is produced by the LDS transpose kernel — avoids the 32x
//  write amplification of strided bf16 stores.)
// ---------------------------------------------------------------------------
__global__ __launch_bounds__(256)
void conv_silu_t(const bf16* __restrict__ xssmT, const float* __restrict__ cw,
                 const float* __restrict__ cb, bf16* __restrict__ uT)
{
  const int i = blockIdx.x;
  const int t = blockIdx.y * 256 + threadIdx.x;
  const int s = t & 2047;
  float acc = cb[i];
  #pragma unroll
  for (int kk = 0; kk < 4; kk++) {
    if (s - 3 + kk >= 0)
      acc += s2f(__builtin_bit_cast(short, xssmT[(size_t)i * 4096 + t - 3 + kk])) * cw[i * 4 + kk];
  }
  const float sig = 1.f / (1.f + __expf(-acc));
  uT[(size_t)i * 4096 + t] = f2b(acc * sig);
}

// ---------------------------------------------------------------------------
// bf16 transpose: in[R][C] -> out[C][R]. 64x64 LDS tiles, 256 threads.
// ---------------------------------------------------------------------------
__global__ __launch_bounds__(256)
void transpose_bf16(const bf16* __restrict__ in, bf16* __restrict__ out,
                    int R, int C)
{
  __shared__ bf16 tile[64][65];
  const int c0 = blockIdx.x * 64, r0 = blockIdx.y * 64;
  #pragma unroll
  for (int it = 0; it < 2; it++) {
    const int linear = (it * 256 + threadIdx.x) * 8;
    const int r = linear >> 6, cc = linear & 63;
    const short8 v = *(const short8*)(in + (size_t)(r0 + r) * C + c0 + cc);
    #pragma unroll
    for (int k = 0; k < 8; k++)
      tile[r][cc + k] = __builtin_bit_cast(bf16, (unsigned short)v[k]);
  }
  __syncthreads();
  #pragma unroll
  for (int it = 0; it < 2; it++) {
    const int linear = (it * 256 + threadIdx.x) * 8;
    const int oc = linear >> 6, k = linear & 63;
    short8 v;
    #pragma unroll
    for (int kk = 0; kk < 8; kk++)
      v[kk] = (short)__builtin_bit_cast(unsigned short, tile[k + kk][oc]);
    *(short8*)(out + (size_t)(c0 + oc) * R + r0 + k) = v;
  }
}

// ---------------------------------------------------------------------------
// finish_y: out[t][i] = yraw[i][t] * silu(gate[i][t]).  (yraw already holds
// y + u*D from the scan.)  64x64 LDS transpose tiles; memory-bound fusion.
// ---------------------------------------------------------------------------
__global__ __launch_bounds__(256)
void finish_y(const bf16* __restrict__ yT, const bf16* __restrict__ gT,
              bf16* __restrict__ out)
{
  __shared__ bf16 tile[64][65];
  const int t0 = blockIdx.x * 64, i0 = blockIdx.y * 64;
  #pragma unroll
  for (int it = 0; it < 2; it++) {
    const int linear = (it * 256 + threadIdx.x) * 8;
    const int r = linear >> 6, cc = linear & 63;
    const size_t off = (size_t)(i0 + r) * 4096 + t0 + cc;
    const short8 y8 = *(const short8*)(yT + off);
    const short8 g8 = *(const short8*)(gT + off);
    #pragma unroll
    for (int k = 0; k < 8; k++) {
      const float g  = s2f(g8[k]);
      const float gs = g / (1.f + __expf(-g));
      tile[r][cc + k] = f2b(s2f(y8[k]) * gs);
    }
  }
  __syncthreads();
  #pragma unroll
  for (int it = 0; it < 2; it++) {
    const int linear = (it * 256 + threadIdx.x) * 8;
    const int oc = linear >> 6, k = linear & 63;
    short8 v;
    #pragma unroll
    for (int kk = 0; kk < 8; kk++)
      v[kk] = (short)__builtin_bit_cast(unsigned short, tile[k + kk][oc]);
    *(short8*)(out + (size_t)(t0 + oc) * 2048 + i0 + k) = v;
  }
}

// ---------------------------------------------------------------------------
// Chunked two-pass selective scan, channel-major I/O. One block per (b,i);
// 256 threads = 16 n x 16 chunks of 128. Emits RAW y + u*D (gate applied in
// finish_y). All streams contiguous in t, vectorized short8 per 8 steps.
// ---------------------------------------------------------------------------
__global__ __launch_bounds__(256)
void ssm_scan(const bf16* __restrict__ dltT, const bf16* __restrict__ uT,
              const bf16* __restrict__ prmT, const float* __restrict__ A_log,
              const float* __restrict__ Dv, bf16* __restrict__ youtT)
{
  __shared__ float Pl[16][17], Fl[16][17], Il[16][17];
  const int blk = blockIdx.x;          // b*2048 + i
  const int b = blk >> 11, i = blk & 2047;
  const int n = threadIdx.x & 15, c = threadIdx.x >> 4;
  const float a  = -__expf(A_log[i * 16 + n]);
  const float Di = Dv[i];
  const size_t rowoff = (size_t)b * 2048 + c * 128;
  const bf16* dp = dltT  + (size_t)i * 4096 + rowoff;
  const bf16* up = uT    + (size_t)i * 4096 + rowoff;
  const bf16* Bp = prmT  + (size_t)(64 + n) * 4096 + rowoff;
  const bf16* Cp = prmT  + (size_t)(80 + n) * 4096 + rowoff;
  bf16*       yp = youtT + (size_t)i * 4096 + rowoff;

  // pass 1: local scan from zero -> decay product P, final state F
  float P = 1.f, F = 0.f;
  for (int j0 = 0; j0 < 128; j0 += 8) {
    const short8 d8 = *(const short8*)(dp + j0);
    const short8 u8 = *(const short8*)(up + j0);
    const short8 B8 = *(const short8*)(Bp + j0);
    #pragma unroll
    for (int j = 0; j < 8; j++) {
      const float dt = s2f(d8[j]);
      const float dA = __expf(dt * a);
      P *= dA;
      F = F * dA + dt * s2f(u8[j]) * s2f(B8[j]);
    }
  }
  Pl[n][c] = P; Fl[n][c] = F;
  __syncthreads();

  // combine: serial over 16 chunks, one thread per n
  if (threadIdx.x < 16) {
    const int nn = threadIdx.x;
    float s = 0.f;
    #pragma unroll
    for (int cc = 0; cc < 16; cc++) {
      Il[nn][cc] = s;
      s = Fl[nn][cc] + Pl[nn][cc] * s;
    }
  }
  __syncthreads();

  // pass 2: replay from exact init, emit raw y + u*D
  float state = Il[n][c];
  for (int j0 = 0; j0 < 128; j0 += 8) {
    const short8 d8 = *(const short8*)(dp + j0);
    const short8 u8 = *(const short8*)(up + j0);
    const short8 B8 = *(const short8*)(Bp + j0);
    const short8 C8 = *(const short8*)(Cp + j0);
    short8 o8;
    #pragma unroll
    for (int j = 0; j < 8; j++) {
      const float dt = s2f(d8[j]);
      const float ut = s2f(u8[j]);
      const float dA = __expf(dt * a);
      state = state * dA + dt * ut * s2f(B8[j]);
      float y = state * s2f(C8[j]);
      y += __shfl_xor(y, 1); y += __shfl_xor(y, 2);
      y += __shfl_xor(y, 4); y += __shfl_xor(y, 8);
      o8[j] = f2s(y + ut * Di);
    }
    if (n == 0) *(short8*)(yp + j0) = o8;
  }
}

// ---------------------------------------------------------------------------
__global__ __launch_bounds__(256)
void merge_k(const bf16* __restrict__ attn, const bf16* __restrict__ mamba,
             const float* __restrict__ malpha, bf16* __restrict__ merged)
{
  const size_t idx = (size_t)blockIdx.x * 256 + threadIdx.x;
  const float al = 1.f / (1.f + __expf(-malpha[0]));
  merged[idx] = f2b(al * b2f(attn[idx]) + (1.f - al) * b2f(mamba[idx]));
}

// ---------------------------------------------------------------------------
extern "C" void kernel_launch(void* const* d_in, const int* in_sizes, int n_in,
                              void* d_out, int out_size, void* d_ws, size_t ws_size,
                              hipStream_t stream)
{
  const float* x_f     = (const float*)d_in[0];
  const float* Wm_f    = (const float*)d_in[1];
  const float* Wq_f    = (const float*)d_in[2];
  const float* Wkv_f   = (const float*)d_in[3];
  const float* q_gain  = (const float*)d_in[4];
  const float* conv_w  = (const float*)d_in[5];
  const float* conv_b  = (const float*)d_in[6];
  const float* Wxp_f   = (const float*)d_in[7];
  const float* Wdt_f   = (const float*)d_in[8];
  const float* b_dt    = (const float*)d_in[9];
  const float* A_log   = (const float*)d_in[10];
  const float* Dv      = (const float*)d_in[11];
  const float* Wmo_f   = (const float*)d_in[12];
  const float* Wp_f    = (const float*)d_in[13];
  const float* malpha  = (const float*)d_in[14];

  // Static arena, peak 111 MB. Lifetimes:
  //  [0,8)    xb -> qn            [8,16)  Wm_b -> kn,vtb,Wxp,Wdt,prm,prmT
  //  [16,18)  Wq_b -> Wp_b        [18,19) Wkv_b
  //  [19,35)  xssmT -> ybuf       [35,51) gateT -> mam(35-43), mrg(43-51)
  //  [51,67)  u(token-major) -> ybufT   [67,83) uT
  //  [83,91)  qraw -> attnb       [91,95) kvraw -> Wmo_b
  //  [95,111) dltT
  char* wp = (char*)d_ws;
  bf16*  xb    = (bf16*)(wp + 0 * MB);
  bf16*  Wm_b  = (bf16*)(wp + 8 * MB);
  bf16*  Wq_b  = (bf16*)(wp + 16 * MB);
  bf16*  Wkv_b = (bf16*)(wp + 18 * MB);
  bf16*  xssmT = (bf16*)(wp + 19 * MB);
  bf16*  gateT = (bf16*)(wp + 35 * MB);
  bf16*  u     = (bf16*)(wp + 51 * MB);
  bf16*  uT    = (bf16*)(wp + 67 * MB);
  bf16*  qraw  = (bf16*)(wp + 83 * MB);
  bf16*  kvraw = (bf16*)(wp + 91 * MB);
  bf16*  dltT  = (bf16*)(wp + 95 * MB);
  // reused regions
  bf16*  qn    = (bf16*)(wp + 0 * MB);
  bf16*  kn    = (bf16*)(wp + 8 * MB);
  bf16*  vtb   = (bf16*)(wp + 10 * MB);
  bf16*  Wxp_b = (bf16*)(wp + 12 * MB);
  bf16*  Wdt_b = (bf16*)(wp + 12 * MB + 512 * 1024);
  bf16*  prm   = (bf16*)(wp + 13 * MB);
  bf16*  prmT  = (bf16*)(wp + 13 * MB + 768 * 1024);
  bf16*  Wp_b  = (bf16*)(wp + 16 * MB);
  bf16*  attnb = (bf16*)(wp + 83 * MB);
  bf16*  Wmo_b = (bf16*)(wp + 91 * MB);
  bf16*  ybuf  = (bf16*)(wp + 19 * MB);
  bf16*  ybufT = (bf16*)(wp + 51 * MB);
  bf16*  mam   = (bf16*)(wp + 35 * MB);
  bf16*  mrg   = (bf16*)(wp + 43 * MB);
  (void)ws_size; (void)in_sizes; (void)n_in; (void)out_size;

  auto cast = [&](const float* src, bf16* dst, int n) {
    const int n4 = n >> 2;
    cast_f2b<<<dim3((n4 + 255) / 256), 256, 0, stream>>>(src, dst, n4);
  };
  cast(x_f,   xb,    T_ * 1024);
  cast(Wm_f,  Wm_b,  4096 * 1024);
  cast(Wq_f,  Wq_b,  1024 * 1024);
  cast(Wkv_f, Wkv_b, 512 * 1024);

  // input projections: xssm/gate stored channel-major only
  gemm_nt<1,1><<<dim3(32, 16), 256, 0, stream>>>(xb, 1024, Wm_b,               1024, nullptr, 0, xssmT, 4096, nullptr, T_, 2048, 1024);
  gemm_nt<1,1><<<dim3(32, 16), 256, 0, stream>>>(xb, 1024, Wm_b + 2048 * 1024, 1024, nullptr, 0, gateT, 4096, nullptr, T_, 2048, 1024);
  gemm_nt<1,0><<<dim3(32, 8),  256, 0, stream>>>(xb, 1024, Wq_b,  1024, qraw,  1024, nullptr, 0, nullptr, T_, 1024, 1024);
  gemm_nt<1,0><<<dim3(32, 4),  256, 0, stream>>>(xb, 1024, Wkv_b, 1024, kvraw,  512, nullptr, 0, nullptr, T_,  512, 1024);

  qkv_prep<<<dim3((T_ * 24) / 4), 256, 0, stream>>>(qraw, kvraw, q_gain, qn, kn, vtb);
  conv_silu_t<<<dim3(2048, 16), 256, 0, stream>>>(xssmT, conv_w, conv_b, uT);
  attn_fwd<<<dim3(32, 16, 2), 256, 0, stream>>>(qn, kn, vtb, attnb);
  // token-major u for the xproj GEMM (LDS-tiled transpose, no amplification)
  transpose_bf16<<<dim3(64, 32), 256, 0, stream>>>(uT, u, 2048, 4096);

  cast(Wxp_f, Wxp_b, 96 * 2048);
  cast(Wdt_f, Wdt_b, 2048 * 64);
  cast(Wmo_f, Wmo_b, 1024 * 2048);
  cast(Wp_f,  Wp_b,  1024 * 1024);

  // mamba tail
  gemm_nt<1,2><<<dim3(32, 1),  256, 0, stream>>>(u, 2048, Wxp_b, 2048, prm, 96, prmT, 4096, nullptr, T_, 96, 2048);
  gemm_nt<2,1><<<dim3(32, 16), 256, 0, stream>>>(prm, 96, Wdt_b, 64, nullptr, 0, dltT, 4096, b_dt, T_, 2048, 64);
  ssm_scan<<<dim3(4096), 256, 0, stream>>>(dltT, uT, prmT, A_log, Dv, ybufT);
  finish_y<<<dim3(64, 32), 256, 0, stream>>>(ybufT, gateT, ybuf);
  gemm_nt<1,0><<<dim3(32, 8),  256, 0, stream>>>(ybuf, 2048, Wmo_b, 2048, mam, 1024, nullptr, 0, nullptr, T_, 1024, 2048);

  merge_k<<<dim3(16384), 256, 0, stream>>>(attnb, mam, malpha, mrg);
  gemm_nt<0,0><<<dim3(32, 8),  256, 0, stream>>>(mrg, 1024, Wp_b, 1024, (float*)d_out, 1024, nullptr, 0, nullptr, T_, 1024, 1024);
}

// Round 8
// 898.723 us; speedup vs baseline: 2.4201x; 1.0058x over previous
//
#include <hip/hip_runtime.h>
#include <hip/hip_bf16.h>

#define B_   2
#define S_   2048
#define T_   4096
#define DIM_ 1024
#define H_   16
#define KVH_ 4
#define HD_  64
#define I_   2048
#define N_   16
#define DTR_ 64
#define MB   ((size_t)1 << 20)

typedef __hip_bfloat16 bf16;
typedef __attribute__((ext_vector_type(8))) short short8;   // 8 bf16 (4 VGPRs)
typedef __attribute__((ext_vector_type(4))) short short4v;
typedef __attribute__((ext_vector_type(4))) float f32x4;

__device__ __forceinline__ float b2f(bf16 v){ return __bfloat162float(v); }
__device__ __forceinline__ bf16  f2b(float v){ return __float2bfloat16(v); }
__device__ __forceinline__ float s2f(short s){
  return __builtin_bit_cast(float, ((unsigned int)(unsigned short)s) << 16);
}
__device__ __forceinline__ short f2s(float v){
  return (short)__builtin_bit_cast(unsigned short, f2b(v));
}

__device__ __forceinline__ void async16(const void* g, void* l) {
  __builtin_amdgcn_global_load_lds((__attribute__((address_space(1))) void*)g,
                                   (__attribute__((address_space(3))) void*)l, 16, 0, 0);
}

// ---------------------------------------------------------------------------
// f32 -> bf16 cast, 4 elements/thread
// ---------------------------------------------------------------------------
__global__ __launch_bounds__(256)
void cast_f2b(const float* __restrict__ in, bf16* __restrict__ out, int n4)
{
  const int i = blockIdx.x * 256 + threadIdx.x;
  if (i >= n4) return;
  const float4 v = ((const float4*)in)[i];
  short4v o;
  o.x = f2s(v.x); o.y = f2s(v.y); o.z = f2s(v.z); o.w = f2s(v.w);
  *(short4v*)(out + (size_t)i * 4) = o;
}

// ---------------------------------------------------------------------------
// NT GEMM: C[M,N] = A[M,K] (row-major) * W[N,K]^T (row-major)
// MODE 0: f32   MODE 1: bf16   MODE 2: bf16 softplus(v+bias[col])
// TS 0: normal store   TS 1: transposed store Ct[col][row] (bf16)   TS 2: both
// ---------------------------------------------------------------------------
template<int MODE, int TS>
__global__ __launch_bounds__(256)
void gemm_nt(const bf16* __restrict__ A, int lda,
             const bf16* __restrict__ W, int ldw,
             void* __restrict__ C, int ldc,
             bf16* __restrict__ Ct, int ldt,
             const float* __restrict__ bias,
             int M, int N, int K)
{
  __shared__ __align__(16) bf16 As[128*32];
  __shared__ __align__(16) bf16 Bs[128*32];
  const int tid  = threadIdx.x;
  const int lane = tid & 63;
  const int wave = tid >> 6;
  const int l16  = lane & 15;
  const int quad = lane >> 4;
  const int wm   = (wave >> 1) << 6;
  const int wn   = (wave & 1) << 6;
  const int m0   = blockIdx.x << 7;
  const int n0   = blockIdx.y << 7;

  f32x4 acc[4][4];
  const f32x4 zero = {0.f, 0.f, 0.f, 0.f};
  #pragma unroll
  for (int i = 0; i < 4; i++)
    #pragma unroll
    for (int j = 0; j < 4; j++) acc[i][j] = zero;

  for (int k0 = 0; k0 < K; k0 += 32) {
    #pragma unroll
    for (int p = 0; p < 2; p++) {
      const int linear = ((p << 8) + tid) << 4;   // byte offset in 8KB tile
      const int row    = linear >> 6;             // 64 B per row (32 bf16)
      const int inrow  = linear & 63;
      async16(A + (size_t)(m0 + row) * lda + k0 + (inrow >> 1), (char*)As + linear);
      int wr = n0 + row; if (wr > N - 1) wr = N - 1;   // clamp for N=96
      async16(W + (size_t)wr * ldw + k0 + (inrow >> 1), (char*)Bs + linear);
    }
    __syncthreads();
    short8 af[4], bfr[4];
    #pragma unroll
    for (int mt = 0; mt < 4; mt++)
      af[mt] = *(const short8*)((const char*)As + ((wm + (mt << 4) + l16) << 6) + (quad << 4));
    #pragma unroll
    for (int nt = 0; nt < 4; nt++)
      bfr[nt] = *(const short8*)((const char*)Bs + ((wn + (nt << 4) + l16) << 6) + (quad << 4));
    #pragma unroll
    for (int mt = 0; mt < 4; mt++)
      #pragma unroll
      for (int nt = 0; nt < 4; nt++)
        acc[mt][nt] = __builtin_amdgcn_mfma_f32_16x16x32_bf16(af[mt], bfr[nt], acc[mt][nt], 0, 0, 0);
    __syncthreads();
  }

  #pragma unroll
  for (int mt = 0; mt < 4; mt++) {
    #pragma unroll
    for (int nt = 0; nt < 4; nt++) {
      const int col = n0 + wn + (nt << 4) + l16;
      if (col >= N) continue;
      const int rowbase = m0 + wm + (mt << 4) + (quad << 2);
      float v[4];
      #pragma unroll
      for (int r = 0; r < 4; r++) {
        float t = acc[mt][nt][r];
        if (MODE == 2) {
          t += bias[col];
          t = (t > 20.f) ? t : log1pf(__expf(t));
        }
        v[r] = t;
      }
      if (TS == 0 || TS == 2) {
        #pragma unroll
        for (int r = 0; r < 4; r++) {
          if (MODE == 0) ((float*)C)[(size_t)(rowbase + r) * ldc + col] = v[r];
          else           ((bf16*)C)[(size_t)(rowbase + r) * ldc + col] = f2b(v[r]);
        }
      }
      if (TS >= 1) {
        short4v p;
        #pragma unroll
        for (int r = 0; r < 4; r++) p[r] = f2s(v[r]);
        *(short4v*)(Ct + (size_t)col * ldt + rowbase) = p;
      }
    }
  }
}

// ---------------------------------------------------------------------------
// QKV prep: RMSNorm(q,k) + RoPE(q,k) + q_gain, layout transforms.
// ---------------------------------------------------------------------------
__global__ __launch_bounds__(256)
void qkv_prep(const bf16* __restrict__ qraw, const bf16* __restrict__ kvraw,
              const float* __restrict__ q_gain,
              bf16* __restrict__ qn, bf16* __restrict__ kn, bf16* __restrict__ vt)
{
  const int wid  = blockIdx.x * 4 + (threadIdx.x >> 6);
  const int lane = threadIdx.x & 63;
  const int t    = wid / 24;
  const int slot = wid % 24;
  const int b = t >> 11, s = t & 2047;

  float val;
  if (slot < 16)       val = b2f(qraw [(size_t)t * 1024 + slot * 64 + lane]);
  else if (slot < 20)  val = b2f(kvraw[(size_t)t * 512  + (slot - 16) * 64 + lane]);
  else                 val = b2f(kvraw[(size_t)t * 512  + 256 + (slot - 20) * 64 + lane]);

  if (slot < 20) {
    float ss = val * val;
    #pragma unroll
    for (int off = 32; off; off >>= 1) ss += __shfl_xor(ss, off);
    val *= rsqrtf(ss * (1.0f / 64.0f) + 1.1920929e-07f);
    const int j = lane & 31;
    const float x1 = __shfl(val, j);
    const float x2 = __shfl(val, j + 32);
    const float inv = powf(10000.0f, -(float)j * (1.0f / 32.0f));
    const float ang = (float)s * inv;
    const float c = cosf(ang), sn = sinf(ang);
    val = (lane < 32) ? (x1 * c + x2 * sn) : (x2 * c - x1 * sn);
  }
  if (slot < 16) {
    val *= q_gain[slot];
    qn[((size_t)(b * 16 + slot) * 2048 + s) * 64 + lane] = f2b(val);
  } else if (slot < 20) {
    kn[((size_t)(b * 4 + (slot - 16)) * 2048 + s) * 64 + lane] = f2b(val);
  } else {
    vt[((size_t)(b * 4 + (slot - 20)) * 64 + lane) * 2048 + s] = f2b(val);
  }
}

// ---------------------------------------------------------------------------
// Flash attention v2 (causal, GQA 16->4): WAVE-AUTONOMOUS. Each wave owns 16
// q-rows; NO __syncthreads (P round-trip is wave-private LDS, in-order DS).
// K-tile = 64 cols/iter (4 sub-tiles), softmax reduce amortized across tiles.
// LDS P rows padded to 80 elems (160 B) to break power-of-2 bank aliasing.
// ---------------------------------------------------------------------------
__global__ __launch_bounds__(256)
void attn_fwd(const bf16* __restrict__ qn, const bf16* __restrict__ kn,
              const bf16* __restrict__ vt, bf16* __restrict__ attn)
{
  __shared__ __align__(16) bf16 Plds[4][16][80];
  const int b = blockIdx.z, h = blockIdx.y;
  const int wave = threadIdx.x >> 6, lane = threadIdx.x & 63;
  const int l16 = lane & 15, quad = lane >> 4;
  const int q0 = blockIdx.x * 64 + wave * 16;     // this wave's 16 q-rows
  const int kvh = h >> 2;
  const bf16* Q  = qn + (size_t)(b * 16 + h)  * 2048 * 64;
  const bf16* Kp = kn + (size_t)(b * 4 + kvh) * 2048 * 64;
  const bf16* Vt = vt + (size_t)(b * 4 + kvh) * 64 * 2048;

  const short8 qf0 = *(const short8*)(Q + (size_t)(q0 + l16) * 64 + quad * 8);
  const short8 qf1 = *(const short8*)(Q + (size_t)(q0 + l16) * 64 + 32 + quad * 8);

  f32x4 acc[4];
  const f32x4 zero = {0.f, 0.f, 0.f, 0.f};
  #pragma unroll
  for (int i = 0; i < 4; i++) acc[i] = zero;
  float m_r[4], l_r[4];
  #pragma unroll
  for (int r = 0; r < 4; r++) { m_r[r] = -1e30f; l_r[r] = 0.f; }

  const int kend = q0 + 16;
  for (int kb = 0; kb < kend; kb += 64) {
    // QK^T for 4 sub-tiles of 16 k-rows
    f32x4 s[4];
    #pragma unroll
    for (int t = 0; t < 4; t++) {
      const bf16* kr = Kp + (size_t)(kb + t * 16 + l16) * 64;
      const short8 kf0 = *(const short8*)(kr + quad * 8);
      const short8 kf1 = *(const short8*)(kr + 32 + quad * 8);
      f32x4 sv = zero;
      sv = __builtin_amdgcn_mfma_f32_16x16x32_bf16(qf0, kf0, sv, 0, 0, 0);
      sv = __builtin_amdgcn_mfma_f32_16x16x32_bf16(qf1, kf1, sv, 0, 0, 0);
      s[t] = sv;
    }
    // online softmax per r (chains have ILP across r)
    float alpha[4], p[4][4];
    #pragma unroll
    for (int r = 0; r < 4; r++) {
      const int row = q0 + quad * 4 + r;
      float v[4];
      #pragma unroll
      for (int t = 0; t < 4; t++) {
        float x = s[t][r] * 0.125f;
        if (kb + t * 16 + l16 > row) x = -1e30f;
        v[t] = x;
      }
      float tm = fmaxf(fmaxf(v[0], v[1]), fmaxf(v[2], v[3]));
      tm = fmaxf(tm, __shfl_xor(tm, 1)); tm = fmaxf(tm, __shfl_xor(tm, 2));
      tm = fmaxf(tm, __shfl_xor(tm, 4)); tm = fmaxf(tm, __shfl_xor(tm, 8));
      const float nm = fmaxf(m_r[r], tm);
      alpha[r] = __expf(m_r[r] - nm);
      m_r[r] = nm;
      float ps = 0.f;
      #pragma unroll
      for (int t = 0; t < 4; t++) { p[r][t] = __expf(v[t] - nm); ps += p[r][t]; }
      ps += __shfl_xor(ps, 1); ps += __shfl_xor(ps, 2);
      ps += __shfl_xor(ps, 4); ps += __shfl_xor(ps, 8);
      l_r[r] = l_r[r] * alpha[r] + ps;
    }
    #pragma unroll
    for (int nt = 0; nt < 4; nt++)
      #pragma unroll
      for (int r = 0; r < 4; r++) acc[nt][r] *= alpha[r];

    // P -> wave-private LDS (C-layout rows -> A-layout reads)
    #pragma unroll
    for (int r = 0; r < 4; r++)
      #pragma unroll
      for (int t = 0; t < 4; t++)
        Plds[wave][quad * 4 + r][t * 16 + l16] = f2b(p[r][t]);

    // PV over the two 32-col chunks
    #pragma unroll
    for (int c = 0; c < 2; c++) {
      const short8 pf = *(const short8*)(&Plds[wave][l16][c * 32 + quad * 8]);
      #pragma unroll
      for (int nt = 0; nt < 4; nt++) {
        const short8 vf = *(const short8*)(Vt + (size_t)(nt * 16 + l16) * 2048 + kb + c * 32 + quad * 8);
        acc[nt] = __builtin_amdgcn_mfma_f32_16x16x32_bf16(pf, vf, acc[nt], 0, 0, 0);
      }
    }
  }

  #pragma unroll
  for (int nt = 0; nt < 4; nt++)
    #pragma unroll
    for (int r = 0; r < 4; r++) {
      const int row = q0 + quad * 4 + r;
      attn[((size_t)b * 2048 + row) * 1024 + h * 64 + nt * 16 + l16] = f2b(acc[nt][r] / l_r[r]);
    }
}

// ---------------------------------------------------------------------------
// Depthwise causal conv (K=4) + bias + SiLU, channel-major in/out only.
// ---------------------------------------------------------------------------
__global__ __launch_bounds__(256)
void conv_silu_t(const bf16* __restrict__ xssmT, const float* __restrict__ cw,
                 const float* __restrict__ cb, bf16* __restrict__ uT)
{
  const int i = blockIdx.x;
  const int t = blockIdx.y * 256 + threadIdx.x;
  const int s = t & 2047;
  float acc = cb[i];
  #pragma unroll
  for (int kk = 0; kk < 4; kk++) {
    if (s - 3 + kk >= 0)
      acc += s2f(__builtin_bit_cast(short, xssmT[(size_t)i * 4096 + t - 3 + kk])) * cw[i * 4 + kk];
  }
  const float sig = 1.f / (1.f + __expf(-acc));
  uT[(size_t)i * 4096 + t] = f2b(acc * sig);
}

// ---------------------------------------------------------------------------
// bf16 transpose: in[R][C] -> out[C][R]. 64x64 LDS tiles, 256 threads.
// ---------------------------------------------------------------------------
__global__ __launch_bounds__(256)
void transpose_bf16(const bf16* __restrict__ in, bf16* __restrict__ out,
                    int R, int C)
{
  __shared__ bf16 tile[64][65];
  const int c0 = blockIdx.x * 64, r0 = blockIdx.y * 64;
  #pragma unroll
  for (int it = 0; it < 2; it++) {
    const int linear = (it * 256 + threadIdx.x) * 8;
    const int r = linear >> 6, cc = linear & 63;
    const short8 v = *(const short8*)(in + (size_t)(r0 + r) * C + c0 + cc);
    #pragma unroll
    for (int k = 0; k < 8; k++)
      tile[r][cc + k] = __builtin_bit_cast(bf16, (unsigned short)v[k]);
  }
  __syncthreads();
  #pragma unroll
  for (int it = 0; it < 2; it++) {
    const int linear = (it * 256 + threadIdx.x) * 8;
    const int oc = linear >> 6, k = linear & 63;
    short8 v;
    #pragma unroll
    for (int kk = 0; kk < 8; kk++)
      v[kk] = (short)__builtin_bit_cast(unsigned short, tile[k + kk][oc]);
    *(short8*)(out + (size_t)(c0 + oc) * R + r0 + k) = v;
  }
}

// ---------------------------------------------------------------------------
// finish_y: out[t][i] = yraw[i][t] * silu(gate[i][t])
// ---------------------------------------------------------------------------
__global__ __launch_bounds__(256)
void finish_y(const bf16* __restrict__ yT, const bf16* __restrict__ gT,
              bf16* __restrict__ out)
{
  __shared__ bf16 tile[64][65];
  const int t0 = blockIdx.x * 64, i0 = blockIdx.y * 64;
  #pragma unroll
  for (int it = 0; it < 2; it++) {
    const int linear = (it * 256 + threadIdx.x) * 8;
    const int r = linear >> 6, cc = linear & 63;
    const size_t off = (size_t)(i0 + r) * 4096 + t0 + cc;
    const short8 y8 = *(const short8*)(yT + off);
    const short8 g8 = *(const short8*)(gT + off);
    #pragma unroll
    for (int k = 0; k < 8; k++) {
      const float g  = s2f(g8[k]);
      const float gs = g / (1.f + __expf(-g));
      tile[r][cc + k] = f2b(s2f(y8[k]) * gs);
    }
  }
  __syncthreads();
  #pragma unroll
  for (int it = 0; it < 2; it++) {
    const int linear = (it * 256 + threadIdx.x) * 8;
    const int oc = linear >> 6, k = linear & 63;
    short8 v;
    #pragma unroll
    for (int kk = 0; kk < 8; kk++)
      v[kk] = (short)__builtin_bit_cast(unsigned short, tile[k + kk][oc]);
    *(short8*)(out + (size_t)(t0 + oc) * 2048 + i0 + k) = v;
  }
}

// ---------------------------------------------------------------------------
// Chunked two-pass selective scan, channel-major I/O.
// ---------------------------------------------------------------------------
__global__ __launch_bounds__(256)
void ssm_scan(const bf16* __restrict__ dltT, const bf16* __restrict__ uT,
              const bf16* __restrict__ prmT, const float* __restrict__ A_log,
              const float* __restrict__ Dv, bf16* __restrict__ youtT)
{
  __shared__ float Pl[16][17], Fl[16][17], Il[16][17];
  const int blk = blockIdx.x;          // b*2048 + i
  const int b = blk >> 11, i = blk & 2047;
  const int n = threadIdx.x & 15, c = threadIdx.x >> 4;
  const float a  = -__expf(A_log[i * 16 + n]);
  const float Di = Dv[i];
  const size_t rowoff = (size_t)b * 2048 + c * 128;
  const bf16* dp = dltT  + (size_t)i * 4096 + rowoff;
  const bf16* up = uT    + (size_t)i * 4096 + rowoff;
  const bf16* Bp = prmT  + (size_t)(64 + n) * 4096 + rowoff;
  const bf16* Cp = prmT  + (size_t)(80 + n) * 4096 + rowoff;
  bf16*       yp = youtT + (size_t)i * 4096 + rowoff;

  float P = 1.f, F = 0.f;
  for (int j0 = 0; j0 < 128; j0 += 8) {
    const short8 d8 = *(const short8*)(dp + j0);
    const short8 u8 = *(const short8*)(up + j0);
    const short8 B8 = *(const short8*)(Bp + j0);
    #pragma unroll
    for (int j = 0; j < 8; j++) {
      const float dt = s2f(d8[j]);
      const float dA = __expf(dt * a);
      P *= dA;
      F = F * dA + dt * s2f(u8[j]) * s2f(B8[j]);
    }
  }
  Pl[n][c] = P; Fl[n][c] = F;
  __syncthreads();

  if (threadIdx.x < 16) {
    const int nn = threadIdx.x;
    float s = 0.f;
    #pragma unroll
    for (int cc = 0; cc < 16; cc++) {
      Il[nn][cc] = s;
      s = Fl[nn][cc] + Pl[nn][cc] * s;
    }
  }
  __syncthreads();

  float state = Il[n][c];
  for (int j0 = 0; j0 < 128; j0 += 8) {
    const short8 d8 = *(const short8*)(dp + j0);
    const short8 u8 = *(const short8*)(up + j0);
    const short8 B8 = *(const short8*)(Bp + j0);
    const short8 C8 = *(const short8*)(Cp + j0);
    short8 o8;
    #pragma unroll
    for (int j = 0; j < 8; j++) {
      const float dt = s2f(d8[j]);
      const float ut = s2f(u8[j]);
      const float dA = __expf(dt * a);
      state = state * dA + dt * ut * s2f(B8[j]);
      float y = state * s2f(C8[j]);
      y += __shfl_xor(y, 1); y += __shfl_xor(y, 2);
      y += __shfl_xor(y, 4); y += __shfl_xor(y, 8);
      o8[j] = f2s(y + ut * Di);
    }
    if (n == 0) *(short8*)(yp + j0) = o8;
  }
}

// ---------------------------------------------------------------------------
__global__ __launch_bounds__(256)
void merge_k(const bf16* __restrict__ attn, const bf16* __restrict__ mamba,
             const float* __restrict__ malpha, bf16* __restrict__ merged)
{
  const size_t idx = (size_t)blockIdx.x * 256 + threadIdx.x;
  const float al = 1.f / (1.f + __expf(-malpha[0]));
  merged[idx] = f2b(al * b2f(attn[idx]) + (1.f - al) * b2f(mamba[idx]));
}

// ---------------------------------------------------------------------------
extern "C" void kernel_launch(void* const* d_in, const int* in_sizes, int n_in,
                              void* d_out, int out_size, void* d_ws, size_t ws_size,
                              hipStream_t stream)
{
  const float* x_f     = (const float*)d_in[0];
  const float* Wm_f    = (const float*)d_in[1];
  const float* Wq_f    = (const float*)d_in[2];
  const float* Wkv_f   = (const float*)d_in[3];
  const float* q_gain  = (const float*)d_in[4];
  const float* conv_w  = (const float*)d_in[5];
  const float* conv_b  = (const float*)d_in[6];
  const float* Wxp_f   = (const float*)d_in[7];
  const float* Wdt_f   = (const float*)d_in[8];
  const float* b_dt    = (const float*)d_in[9];
  const float* A_log   = (const float*)d_in[10];
  const float* Dv      = (const float*)d_in[11];
  const float* Wmo_f   = (const float*)d_in[12];
  const float* Wp_f    = (const float*)d_in[13];
  const float* malpha  = (const float*)d_in[14];

  // Static arena, peak 111 MB (same as round 7).
  char* wp = (char*)d_ws;
  bf16*  xb    = (bf16*)(wp + 0 * MB);
  bf16*  Wm_b  = (bf16*)(wp + 8 * MB);
  bf16*  Wq_b  = (bf16*)(wp + 16 * MB);
  bf16*  Wkv_b = (bf16*)(wp + 18 * MB);
  bf16*  xssmT = (bf16*)(wp + 19 * MB);
  bf16*  gateT = (bf16*)(wp + 35 * MB);
  bf16*  u     = (bf16*)(wp + 51 * MB);
  bf16*  uT    = (bf16*)(wp + 67 * MB);
  bf16*  qraw  = (bf16*)(wp + 83 * MB);
  bf16*  kvraw = (bf16*)(wp + 91 * MB);
  bf16*  dltT  = (bf16*)(wp + 95 * MB);
  // reused regions
  bf16*  qn    = (bf16*)(wp + 0 * MB);
  bf16*  kn    = (bf16*)(wp + 8 * MB);
  bf16*  vtb   = (bf16*)(wp + 10 * MB);
  bf16*  Wxp_b = (bf16*)(wp + 12 * MB);
  bf16*  Wdt_b = (bf16*)(wp + 12 * MB + 512 * 1024);
  bf16*  prm   = (bf16*)(wp + 13 * MB);
  bf16*  prmT  = (bf16*)(wp + 13 * MB + 768 * 1024);
  bf16*  Wp_b  = (bf16*)(wp + 16 * MB);
  bf16*  attnb = (bf16*)(wp + 83 * MB);
  bf16*  Wmo_b = (bf16*)(wp + 91 * MB);
  bf16*  ybuf  = (bf16*)(wp + 19 * MB);
  bf16*  ybufT = (bf16*)(wp + 51 * MB);
  bf16*  mam   = (bf16*)(wp + 35 * MB);
  bf16*  mrg   = (bf16*)(wp + 43 * MB);
  (void)ws_size; (void)in_sizes; (void)n_in; (void)out_size;

  auto cast = [&](const float* src, bf16* dst, int n) {
    const int n4 = n >> 2;
    cast_f2b<<<dim3((n4 + 255) / 256), 256, 0, stream>>>(src, dst, n4);
  };
  cast(x_f,   xb,    T_ * 1024);
  cast(Wm_f,  Wm_b,  4096 * 1024);
  cast(Wq_f,  Wq_b,  1024 * 1024);
  cast(Wkv_f, Wkv_b, 512 * 1024);

  gemm_nt<1,1><<<dim3(32, 16), 256, 0, stream>>>(xb, 1024, Wm_b,               1024, nullptr, 0, xssmT, 4096, nullptr, T_, 2048, 1024);
  gemm_nt<1,1><<<dim3(32, 16), 256, 0, stream>>>(xb, 1024, Wm_b + 2048 * 1024, 1024, nullptr, 0, gateT, 4096, nullptr, T_, 2048, 1024);
  gemm_nt<1,0><<<dim3(32, 8),  256, 0, stream>>>(xb, 1024, Wq_b,  1024, qraw,  1024, nullptr, 0, nullptr, T_, 1024, 1024);
  gemm_nt<1,0><<<dim3(32, 4),  256, 0, stream>>>(xb, 1024, Wkv_b, 1024, kvraw,  512, nullptr, 0, nullptr, T_,  512, 1024);

  qkv_prep<<<dim3((T_ * 24) / 4), 256, 0, stream>>>(qraw, kvraw, q_gain, qn, kn, vtb);
  conv_silu_t<<<dim3(2048, 16), 256, 0, stream>>>(xssmT, conv_w, conv_b, uT);
  attn_fwd<<<dim3(32, 16, 2), 256, 0, stream>>>(qn, kn, vtb, attnb);
  transpose_bf16<<<dim3(64, 32), 256, 0, stream>>>(uT, u, 2048, 4096);

  cast(Wxp_f, Wxp_b, 96 * 2048);
  cast(Wdt_f, Wdt_b, 2048 * 64);
  cast(Wmo_f, Wmo_b, 1024 * 2048);
  cast(Wp_f,  Wp_b,  1024 * 1024);

  gemm_nt<1,2><<<dim3(32, 1),  256, 0, stream>>>(u, 2048, Wxp_b, 2048, prm, 96, prmT, 4096, nullptr, T_, 96, 2048);
  gemm_nt<2,1><<<dim3(32, 16), 256, 0, stream>>>(prm, 96, Wdt_b, 64, nullptr, 0, dltT, 4096, b_dt, T_, 2048, 64);
  ssm_scan<<<dim3(4096), 256, 0, stream>>>(dltT, uT, prmT, A_log, Dv, ybufT);
  finish_y<<<dim3(64, 32), 256, 0, stream>>>(ybufT, gateT, ybuf);
  gemm_nt<1,0><<<dim3(32, 8),  256, 0, stream>>>(ybuf, 2048, Wmo_b, 2048, mam, 1024, nullptr, 0, nullptr, T_, 1024, 2048);

  merge_k<<<dim3(16384), 256, 0, stream>>>(attnb, mam, malpha, mrg);
  gemm_nt<0,0><<<dim3(32, 8),  256, 0, stream>>>(mrg, 1024, Wp_b, 1024, (float*)d_out, 1024, nullptr, 0, nullptr, T_, 1024, 1024);
}